// Round 1
// baseline (1144.288 us; speedup 1.0000x reference)
//
#include <hip/hip_runtime.h>
#include <cstdint>
#include <cstddef>

#define NN 50000
#define NE 600000
#define NT (NE + NN)          // 650000 edges incl. self loops
#define NG 1024
#define D 128
#define NEG_SLOPE 0.2f

// ---------- helpers: order-preserving float<->uint encoding for atomicMax ----
__device__ __forceinline__ unsigned fenc(float f) {
    unsigned u = __float_as_uint(f);
    return (u & 0x80000000u) ? ~u : (u | 0x80000000u);
}
__device__ __forceinline__ float fdec(unsigned x) {
    return __uint_as_float((x & 0x80000000u) ? (x ^ 0x80000000u) : ~x);
}

// ---------- zero a float4 region ----------
__global__ void zero_kernel(float4* __restrict__ p, int n4) {
    int i = blockIdx.x * blockDim.x + threadIdx.x;
    int stride = gridDim.x * blockDim.x;
    float4 z = {0.f, 0.f, 0.f, 0.f};
    for (; i < n4; i += stride) p[i] = z;
}

// ---------- GEMM h = X @ W  (+ per-row dots with a_src / a_dst) ----------
#define GROWS 64
__global__ __launch_bounds__(256) void gemm_alpha(
    const float* __restrict__ X, const float* __restrict__ W,
    const float* __restrict__ asv, const float* __restrict__ adv,
    float* __restrict__ H, float* __restrict__ AS, float* __restrict__ AD)
{
    __shared__ float Wl[D * D];      // 64 KB
    __shared__ float red[4][2];
    int t = threadIdx.x;
    for (int i = t; i < D * D; i += 256) Wl[i] = W[i];
    __syncthreads();

    int sub  = t >> 7;       // which row of the pair
    int c    = t & 127;      // output column
    int wid  = t >> 6;       // wave id in block (0..3)
    int lane = t & 63;
    float asc = asv[c], adc = adv[c];
    int r0 = blockIdx.x * GROWS;

    for (int rr = 0; rr < GROWS; rr += 2) {
        int r = r0 + rr + sub;
        bool ok = r < NN;
        const float* xr = X + (size_t)(ok ? r : 0) * D;
        float acc = 0.f;
        #pragma unroll 8
        for (int k = 0; k < D; k += 4) {
            float4 xv = *reinterpret_cast<const float4*>(xr + k);
            acc += xv.x * Wl[(k + 0) * D + c];
            acc += xv.y * Wl[(k + 1) * D + c];
            acc += xv.z * Wl[(k + 2) * D + c];
            acc += xv.w * Wl[(k + 3) * D + c];
        }
        if (ok) H[(size_t)r * D + c] = acc;

        // reduce acc*asc, acc*adc across the row's 128 threads (2 waves)
        float s1 = acc * asc, s2 = acc * adc;
        #pragma unroll
        for (int off = 32; off > 0; off >>= 1) {
            s1 += __shfl_down(s1, off, 64);
            s2 += __shfl_down(s2, off, 64);
        }
        if (lane == 0) { red[wid][0] = s1; red[wid][1] = s2; }
        __syncthreads();
        if (ok && c == 0) {
            int w0 = sub * 2;
            AS[r] = red[w0][0] + red[w0 + 1][0];
            AD[r] = red[w0][1] + red[w0 + 1][1];
        }
        __syncthreads();
    }
}

// ---------- edge pass 1: segment max of leaky_relu scores ----------
__global__ void edge_max(const int* __restrict__ ei0, const int* __restrict__ ei1,
                         const float* __restrict__ AS, const float* __restrict__ AD,
                         unsigned* __restrict__ EMAX)
{
    int e = blockIdx.x * blockDim.x + threadIdx.x;
    if (e >= NT) return;
    int s, d;
    if (e < NE) { s = ei0[e]; d = ei1[e]; } else { s = d = e - NE; }
    float v = AS[s] + AD[d];
    v = v > 0.f ? v : v * NEG_SLOPE;
    atomicMax(EMAX + d, fenc(v));
}

// ---------- edge pass 2: exp and segment sum ----------
__global__ void edge_expsum(const int* __restrict__ ei0, const int* __restrict__ ei1,
                            const float* __restrict__ AS, const float* __restrict__ AD,
                            const unsigned* __restrict__ EMAX,
                            float* __restrict__ EX, float* __restrict__ DEN)
{
    int e = blockIdx.x * blockDim.x + threadIdx.x;
    if (e >= NT) return;
    int s, d;
    if (e < NE) { s = ei0[e]; d = ei1[e]; } else { s = d = e - NE; }
    float v = AS[s] + AD[d];
    v = v > 0.f ? v : v * NEG_SLOPE;
    float ex = expf(v - fdec(EMAX[d]));
    EX[e] = ex;
    atomicAdd(DEN + d, ex);
}

// ---------- edge pass 3: weighted scatter-add of h[src] into out[dst] -------
__global__ __launch_bounds__(256) void aggregate(
    const int* __restrict__ ei0, const int* __restrict__ ei1,
    const float* __restrict__ EX, const float* __restrict__ DEN,
    const float* __restrict__ H, float* __restrict__ OUT)
{
    int e = (int)((blockIdx.x * blockDim.x + threadIdx.x) >> 6);
    int lane = threadIdx.x & 63;
    if (e >= NT) return;
    int s, d;
    if (e < NE) { s = ei0[e]; d = ei1[e]; } else { s = d = e - NE; }
    float alpha = EX[e] / DEN[d];
    const float* hs = H + (size_t)s * D;
    float* od = OUT + (size_t)d * D;
    atomicAdd(od + lane,      hs[lane]      * alpha);
    atomicAdd(od + lane + 64, hs[lane + 64] * alpha);
}

// ---------- bias + relu (in place) + pooled sum ----------
__global__ void bias_relu_pool(const float* __restrict__ B, const int* __restrict__ batch,
                               float* __restrict__ AGG, float* __restrict__ ESUM,
                               float* __restrict__ CNT)
{
    int idx = blockIdx.x * blockDim.x + threadIdx.x;
    int r = idx >> 7, c = idx & 127;
    if (r >= NN) return;
    float v = AGG[(size_t)r * D + c] + B[c];
    v = v > 0.f ? v : 0.f;
    AGG[(size_t)r * D + c] = v;
    int g = batch[r];
    atomicAdd(ESUM + (size_t)g * D + c, v);
    if (c == 0) atomicAdd(CNT + g, 1.0f);
}

// ---------- final divide ----------
__global__ void pool_div(const float* __restrict__ ESUM, const float* __restrict__ CNT,
                         float* __restrict__ OUT)
{
    int idx = blockIdx.x * blockDim.x + threadIdx.x;
    if (idx >= NG * D) return;
    int g = idx >> 7;
    float cnt = CNT[g];
    cnt = cnt > 1.f ? cnt : 1.f;
    OUT[idx] = ESUM[idx] / cnt;
}

extern "C" void kernel_launch(void* const* d_in, const int* in_sizes, int n_in,
                              void* d_out, int out_size, void* d_ws, size_t ws_size,
                              hipStream_t stream)
{
    const float* x     = (const float*)d_in[0];
    const int*   ei    = (const int*)d_in[1];
    const int*   batch = (const int*)d_in[2];
    const float* W[2]    = { (const float*)d_in[3], (const float*)d_in[7] };
    const float* ASV[2]  = { (const float*)d_in[4], (const float*)d_in[8] };
    const float* ADV[2]  = { (const float*)d_in[5], (const float*)d_in[9] };
    const float* BV[2]   = { (const float*)d_in[6], (const float*)d_in[10] };
    float* out = (float*)d_out;
    float* ws  = (float*)d_ws;

    const int* ei0 = ei;
    const int* ei1 = ei + NE;

    // workspace layout (floats)
    size_t o = 0;
    float*    hbuf = ws + o;       o += (size_t)NN * D;       // 6.4M
    float*    agg  = ws + o;       o += (size_t)NN * D;       // 6.4M
    float*    den  = ws + o;       o += NN;
    unsigned* emax = (unsigned*)(ws + o); o += NN;
    float*    esum = ws + o;       o += (size_t)NG * D;
    float*    cnt  = ws + o;       o += NG;
    float*    ex   = ws + o;       o += NT;
    float*    asb  = ws + o;       o += NN;
    float*    adb  = ws + o;       o += NN;

    // contiguous zero region: agg .. cnt
    const int zero_floats = NN * D + NN + NN + NG * D + NG;   // 6,632,096
    const int zero_f4 = zero_floats / 4;

    const int gemm_blocks = (NN + GROWS - 1) / GROWS;
    const int edge_blocks = (NT + 255) / 256;
    const int agg_blocks  = (NT + 3) / 4;          // 4 edges (waves) per block
    const int brp_blocks  = (NN * D) / 256;
    const int pd_blocks   = (NG * D + 255) / 256;

    for (int layer = 0; layer < 2; ++layer) {
        const float* Xin = (layer == 0) ? x : agg;   // layer-2 input is h1 (in agg)
        // GEMM first (reads agg for layer 2), then zero accumulators
        gemm_alpha<<<gemm_blocks, 256, 0, stream>>>(Xin, W[layer], ASV[layer], ADV[layer],
                                                    hbuf, asb, adb);
        zero_kernel<<<2048, 256, 0, stream>>>((float4*)agg, zero_f4);
        edge_max<<<edge_blocks, 256, 0, stream>>>(ei0, ei1, asb, adb, emax);
        edge_expsum<<<edge_blocks, 256, 0, stream>>>(ei0, ei1, asb, adb, emax, ex, den);
        aggregate<<<agg_blocks, 256, 0, stream>>>(ei0, ei1, ex, den, hbuf, agg);
        bias_relu_pool<<<brp_blocks, 256, 0, stream>>>(BV[layer], batch, agg, esum, cnt);
        pool_div<<<pd_blocks, 256, 0, stream>>>(esum, cnt, out + (size_t)layer * NG * D);
    }
}

// Round 2
// 565.934 us; speedup vs baseline: 2.0219x; 2.0219x over previous
//
#include <hip/hip_runtime.h>
#include <cstdint>
#include <cstddef>

#define NN 50000
#define NE 600000
#define NT (NE + NN)          // 650000 edges incl. self loops
#define NG 1024
#define D 128
#define NEG_SLOPE 0.2f

// ---------- zero a float4 region ----------
__global__ void zero_kernel(float4* __restrict__ p, int n4) {
    int i = blockIdx.x * blockDim.x + threadIdx.x;
    int stride = gridDim.x * blockDim.x;
    float4 z = {0.f, 0.f, 0.f, 0.f};
    for (; i < n4; i += stride) p[i] = z;
}

// ---------- CSR build: histogram of dst ----------
__global__ void hist_kernel(const int* __restrict__ ei1, unsigned* __restrict__ deg) {
    int e = blockIdx.x * blockDim.x + threadIdx.x;
    if (e >= NT) return;
    int d = (e < NE) ? ei1[e] : (e - NE);
    atomicAdd(deg + d, 1u);
}

// ---------- scan pass 1: per-256-chunk inclusive scan + chunk totals ----------
__global__ void scan1(const unsigned* __restrict__ deg, unsigned* __restrict__ chunk,
                      unsigned* __restrict__ partials) {
    __shared__ unsigned sm[256];
    int i = blockIdx.x * 256 + threadIdx.x;
    unsigned v = (i < NN) ? deg[i] : 0u;
    sm[threadIdx.x] = v;
    __syncthreads();
    for (int off = 1; off < 256; off <<= 1) {
        unsigned t = (threadIdx.x >= off) ? sm[threadIdx.x - off] : 0u;
        __syncthreads();
        sm[threadIdx.x] += t;
        __syncthreads();
    }
    if (i < NN) chunk[i] = sm[threadIdx.x];
    if (threadIdx.x == 255) partials[blockIdx.x] = sm[255];
}

// ---------- scan pass 2: single-block scan of chunk totals ----------
__global__ void scan2(unsigned* __restrict__ partials, int nb) {
    __shared__ unsigned sm[256];
    int i = threadIdx.x;
    sm[i] = (i < nb) ? partials[i] : 0u;
    __syncthreads();
    for (int off = 1; off < 256; off <<= 1) {
        unsigned t = (i >= off) ? sm[i - off] : 0u;
        __syncthreads();
        sm[i] += t;
        __syncthreads();
    }
    if (i < nb) partials[i] = sm[i];
}

// ---------- scan pass 3: exclusive ptr + fill cursor ----------
__global__ void scan3(const unsigned* __restrict__ chunk, const unsigned* __restrict__ deg,
                      const unsigned* __restrict__ pscan, int* __restrict__ ptr,
                      int* __restrict__ fill) {
    int i = blockIdx.x * 256 + threadIdx.x;
    if (i < NN) {
        unsigned off = blockIdx.x ? pscan[blockIdx.x - 1] : 0u;
        int excl = (int)(chunk[i] - deg[i] + off);
        ptr[i] = excl;
        fill[i] = excl;
    }
    if (i == 0) ptr[NN] = NT;
}

// ---------- CSR build: scatter src indices ----------
__global__ void scatter_kernel(const int* __restrict__ ei0, const int* __restrict__ ei1,
                               int* __restrict__ fill, int* __restrict__ csr_src) {
    int e = blockIdx.x * blockDim.x + threadIdx.x;
    if (e >= NT) return;
    int s, d;
    if (e < NE) { s = ei0[e]; d = ei1[e]; } else { s = d = e - NE; }
    int pos = atomicAdd(fill + d, 1);
    csr_src[pos] = s;
}

// ---------- per-graph node counts (float) ----------
__global__ void cnt_kernel(const int* __restrict__ batch, float* __restrict__ cnt) {
    int r = blockIdx.x * blockDim.x + threadIdx.x;
    if (r >= NN) return;
    atomicAdd(cnt + batch[r], 1.0f);
}

// ---------- GEMM h = X @ W  (+ per-row dots with a_src / a_dst) ----------
#define GROWS 64
__global__ __launch_bounds__(256) void gemm_alpha(
    const float* __restrict__ X, const float* __restrict__ W,
    const float* __restrict__ asv, const float* __restrict__ adv,
    float* __restrict__ H, float* __restrict__ AS, float* __restrict__ AD)
{
    __shared__ float Wl[D * D];      // 64 KB
    __shared__ float red[4][2];
    int t = threadIdx.x;
    for (int i = t; i < D * D; i += 256) Wl[i] = W[i];
    __syncthreads();

    int sub  = t >> 7;       // which row of the pair
    int c    = t & 127;      // output column
    int wid  = t >> 6;       // wave id in block (0..3)
    int lane = t & 63;
    float asc = asv[c], adc = adv[c];
    int r0 = blockIdx.x * GROWS;

    for (int rr = 0; rr < GROWS; rr += 2) {
        int r = r0 + rr + sub;
        bool ok = r < NN;
        const float* xr = X + (size_t)(ok ? r : 0) * D;
        float acc = 0.f;
        #pragma unroll 8
        for (int k = 0; k < D; k += 4) {
            float4 xv = *reinterpret_cast<const float4*>(xr + k);
            acc += xv.x * Wl[(k + 0) * D + c];
            acc += xv.y * Wl[(k + 1) * D + c];
            acc += xv.z * Wl[(k + 2) * D + c];
            acc += xv.w * Wl[(k + 3) * D + c];
        }
        if (ok) H[(size_t)r * D + c] = acc;

        float s1 = acc * asc, s2 = acc * adc;
        #pragma unroll
        for (int off = 32; off > 0; off >>= 1) {
            s1 += __shfl_down(s1, off, 64);
            s2 += __shfl_down(s2, off, 64);
        }
        if (lane == 0) { red[wid][0] = s1; red[wid][1] = s2; }
        __syncthreads();
        if (ok && c == 0) {
            int w0 = sub * 2;
            AS[r] = red[w0][0] + red[w0 + 1][0];
            AD[r] = red[w0][1] + red[w0 + 1][1];
        }
        __syncthreads();
    }
}

// ---------- fused per-node: online softmax + weighted gather + bias + relu
//            + pooled-sum atomic.  One wave per dst node, 2 dims per lane. ----
__global__ __launch_bounds__(256) void gat_node(
    const int* __restrict__ ptr, const int* __restrict__ csr_src,
    const float* __restrict__ AS, const float* __restrict__ AD,
    const float* __restrict__ H, const float* __restrict__ B,
    const int* __restrict__ batch, float* __restrict__ HOUT,
    float* __restrict__ ESUM)
{
    int nid  = (int)((blockIdx.x * blockDim.x + threadIdx.x) >> 6);
    int lane = threadIdx.x & 63;
    if (nid >= NN) return;

    int beg = ptr[nid], end = ptr[nid + 1];
    float ad_d = AD[nid];

    float m = -3.0e38f, den = 0.f, a0 = 0.f, a1 = 0.f;
    int s = csr_src[beg];
    for (int j = beg; j < end; ++j) {
        int snext = (j + 1 < end) ? csr_src[j + 1] : 0;
        float e = AS[s] + ad_d;
        e = e > 0.f ? e : e * NEG_SLOPE;
        float mn = fmaxf(m, e);
        float f = __expf(m - mn);
        float w = __expf(e - mn);
        const float* hs = H + (size_t)s * D;
        float h0 = hs[lane], h1 = hs[lane + 64];
        den = den * f + w;
        a0  = a0  * f + w * h0;
        a1  = a1  * f + w * h1;
        m = mn;
        s = snext;
    }
    float inv = 1.0f / den;   // >=1 edge guaranteed (self loop)
    float o0 = fmaxf(a0 * inv + B[lane],      0.f);
    float o1 = fmaxf(a1 * inv + B[lane + 64], 0.f);
    HOUT[(size_t)nid * D + lane]      = o0;
    HOUT[(size_t)nid * D + lane + 64] = o1;
    int g = batch[nid];
    atomicAdd(ESUM + (size_t)g * D + lane,      o0);
    atomicAdd(ESUM + (size_t)g * D + lane + 64, o1);
}

// ---------- final divide ----------
__global__ void pool_div(const float* __restrict__ ESUM, const float* __restrict__ CNT,
                         float* __restrict__ OUT)
{
    int idx = blockIdx.x * blockDim.x + threadIdx.x;
    if (idx >= NG * D) return;
    int g = idx >> 7;
    float cnt = CNT[g];
    cnt = cnt > 1.f ? cnt : 1.f;
    OUT[idx] = ESUM[idx] / cnt;
}

extern "C" void kernel_launch(void* const* d_in, const int* in_sizes, int n_in,
                              void* d_out, int out_size, void* d_ws, size_t ws_size,
                              hipStream_t stream)
{
    const float* x     = (const float*)d_in[0];
    const int*   ei    = (const int*)d_in[1];
    const int*   batch = (const int*)d_in[2];
    const float* W[2]    = { (const float*)d_in[3], (const float*)d_in[7] };
    const float* ASV[2]  = { (const float*)d_in[4], (const float*)d_in[8] };
    const float* ADV[2]  = { (const float*)d_in[5], (const float*)d_in[9] };
    const float* BV[2]   = { (const float*)d_in[6], (const float*)d_in[10] };
    float* out = (float*)d_out;
    float* ws  = (float*)d_ws;

    const int* ei0 = ei;
    const int* ei1 = ei + NE;

    const int NB = (NN + 255) / 256;     // 196 scan chunks

    // ---- workspace layout (32-bit words) ----
    size_t o = 0;
    // zero region (contiguous, zeroed once per call): deg, cnt, esum[2]
    unsigned* deg   = (unsigned*)(ws + o); o += NN;               // 50000
    float*    cnt   = ws + o;              o += NG;               // 1024
    float*    esum0 = ws + o;              o += (size_t)NG * D;   // 131072
    float*    esum1 = ws + o;              o += (size_t)NG * D;   // 131072
    const size_t zero_words = o;                                  // 313168 (mult of 4)

    float*    hbuf  = ws + o;              o += (size_t)NN * D;   // gemm out
    float*    hout  = ws + o;              o += (size_t)NN * D;   // gat out (layer1 h)
    float*    asb   = ws + o;              o += NN;
    float*    adb   = ws + o;              o += NN;
    unsigned* chunk = (unsigned*)(ws + o); o += NN;
    int*      ptr   = (int*)(ws + o);      o += NN + 1;
    int*      fill  = (int*)(ws + o);      o += NN;
    int*      csr   = (int*)(ws + o);      o += NT;
    unsigned* parts = (unsigned*)(ws + o); o += 256;

    const int edge_blocks = (NT + 255) / 256;
    const int gemm_blocks = (NN + GROWS - 1) / GROWS;
    const int gat_blocks  = (NN + 3) / 4;          // 4 waves (nodes) per block
    const int pd_blocks   = (NG * D + 255) / 256;

    // ---- one-time (per call) graph prep ----
    zero_kernel<<<256, 256, 0, stream>>>((float4*)ws, (int)(zero_words / 4));
    hist_kernel<<<edge_blocks, 256, 0, stream>>>(ei1, deg);
    cnt_kernel<<<NB, 256, 0, stream>>>(batch, cnt);
    scan1<<<NB, 256, 0, stream>>>(deg, chunk, parts);
    scan2<<<1, 256, 0, stream>>>(parts, NB);
    scan3<<<NB, 256, 0, stream>>>(chunk, deg, parts, ptr, fill);
    scatter_kernel<<<edge_blocks, 256, 0, stream>>>(ei0, ei1, fill, csr);

    // ---- layer 1 ----
    gemm_alpha<<<gemm_blocks, 256, 0, stream>>>(x, W[0], ASV[0], ADV[0], hbuf, asb, adb);
    gat_node<<<gat_blocks, 256, 0, stream>>>(ptr, csr, asb, adb, hbuf, BV[0], batch,
                                             hout, esum0);
    pool_div<<<pd_blocks, 256, 0, stream>>>(esum0, cnt, out);

    // ---- layer 2 (input = hout; gat output may overwrite hout safely) ----
    gemm_alpha<<<gemm_blocks, 256, 0, stream>>>(hout, W[1], ASV[1], ADV[1], hbuf, asb, adb);
    gat_node<<<gat_blocks, 256, 0, stream>>>(ptr, csr, asb, adb, hbuf, BV[1], batch,
                                             hout, esum1);
    pool_div<<<pd_blocks, 256, 0, stream>>>(esum1, cnt, out + (size_t)NG * D);
}

// Round 3
// 348.474 us; speedup vs baseline: 3.2837x; 1.6240x over previous
//
#include <hip/hip_runtime.h>
#include <cstdint>
#include <cstddef>

#define NN 50000
#define NE 600000
#define NT (NE + NN)          // 650000 edges incl. self loops
#define NG 1024
#define D 128
#define NEG_SLOPE 0.2f

// ---------- zero a float4 region ----------
__global__ void zero_kernel(float4* __restrict__ p, int n4) {
    int i = blockIdx.x * blockDim.x + threadIdx.x;
    int stride = gridDim.x * blockDim.x;
    float4 z = {0.f, 0.f, 0.f, 0.f};
    for (; i < n4; i += stride) p[i] = z;
}

// ---------- CSR build: histogram of dst ----------
__global__ void hist_kernel(const int* __restrict__ ei1, unsigned* __restrict__ deg) {
    int e = blockIdx.x * blockDim.x + threadIdx.x;
    if (e >= NT) return;
    int d = (e < NE) ? ei1[e] : (e - NE);
    atomicAdd(deg + d, 1u);
}

// ---------- scan pass 1 ----------
__global__ void scan1(const unsigned* __restrict__ deg, unsigned* __restrict__ chunk,
                      unsigned* __restrict__ partials) {
    __shared__ unsigned sm[256];
    int i = blockIdx.x * 256 + threadIdx.x;
    unsigned v = (i < NN) ? deg[i] : 0u;
    sm[threadIdx.x] = v;
    __syncthreads();
    for (int off = 1; off < 256; off <<= 1) {
        unsigned t = (threadIdx.x >= off) ? sm[threadIdx.x - off] : 0u;
        __syncthreads();
        sm[threadIdx.x] += t;
        __syncthreads();
    }
    if (i < NN) chunk[i] = sm[threadIdx.x];
    if (threadIdx.x == 255) partials[blockIdx.x] = sm[255];
}

// ---------- scan pass 2 ----------
__global__ void scan2(unsigned* __restrict__ partials, int nb) {
    __shared__ unsigned sm[256];
    int i = threadIdx.x;
    sm[i] = (i < nb) ? partials[i] : 0u;
    __syncthreads();
    for (int off = 1; off < 256; off <<= 1) {
        unsigned t = (i >= off) ? sm[i - off] : 0u;
        __syncthreads();
        sm[i] += t;
        __syncthreads();
    }
    if (i < nb) partials[i] = sm[i];
}

// ---------- scan pass 3 ----------
__global__ void scan3(const unsigned* __restrict__ chunk, const unsigned* __restrict__ deg,
                      const unsigned* __restrict__ pscan, int* __restrict__ ptr,
                      int* __restrict__ fill) {
    int i = blockIdx.x * 256 + threadIdx.x;
    if (i < NN) {
        unsigned off = blockIdx.x ? pscan[blockIdx.x - 1] : 0u;
        int excl = (int)(chunk[i] - deg[i] + off);
        ptr[i] = excl;
        fill[i] = excl;
    }
    if (i == 0) ptr[NN] = NT;
}

// ---------- CSR build: scatter src indices ----------
__global__ void scatter_kernel(const int* __restrict__ ei0, const int* __restrict__ ei1,
                               int* __restrict__ fill, int* __restrict__ csr_src) {
    int e = blockIdx.x * blockDim.x + threadIdx.x;
    if (e >= NT) return;
    int s, d;
    if (e < NE) { s = ei0[e]; d = ei1[e]; } else { s = d = e - NE; }
    int pos = atomicAdd(fill + d, 1);
    csr_src[pos] = s;
}

// ---------- per-graph node counts ----------
__global__ void cnt_kernel(const int* __restrict__ batch, float* __restrict__ cnt) {
    int r = blockIdx.x * blockDim.x + threadIdx.x;
    if (r >= NN) return;
    atomicAdd(cnt + batch[r], 1.0f);
}

// ---------- tiny: wsv = W @ a_src, wdv = W @ a_dst ----------
__global__ void wvec_kernel(const float* __restrict__ W, const float* __restrict__ a_s,
                            const float* __restrict__ a_d,
                            float* __restrict__ wsv, float* __restrict__ wdv) {
    int k = threadIdx.x;
    if (k >= D) return;
    float s1 = 0.f, s2 = 0.f;
    for (int c = 0; c < D; c += 4) {
        float4 w   = *reinterpret_cast<const float4*>(W + (size_t)k * D + c);
        float4 as4 = *reinterpret_cast<const float4*>(a_s + c);
        float4 ad4 = *reinterpret_cast<const float4*>(a_d + c);
        s1 += w.x * as4.x + w.y * as4.y + w.z * as4.z + w.w * as4.w;
        s2 += w.x * ad4.x + w.y * ad4.y + w.z * ad4.z + w.w * ad4.w;
    }
    wsv[k] = s1; wdv[k] = s2;
}

// ---------- AS[r] = X[r]·wsv, AD[r] = X[r]·wdv  (one wave per row) ----------
__global__ __launch_bounds__(256) void row_dots(
    const float* __restrict__ X, const float* __restrict__ wsv,
    const float* __restrict__ wdv, float* __restrict__ AS, float* __restrict__ AD)
{
    int r = blockIdx.x * 4 + (threadIdx.x >> 6);
    int lane = threadIdx.x & 63;
    if (r >= NN) return;
    float2 x  = *reinterpret_cast<const float2*>(X + (size_t)r * D + lane * 2);
    float2 ws = *reinterpret_cast<const float2*>(wsv + lane * 2);
    float2 wd = *reinterpret_cast<const float2*>(wdv + lane * 2);
    float s1 = x.x * ws.x + x.y * ws.y;
    float s2 = x.x * wd.x + x.y * wd.y;
    #pragma unroll
    for (int off = 32; off; off >>= 1) {
        s1 += __shfl_down(s1, off, 64);
        s2 += __shfl_down(s2, off, 64);
    }
    if (lane == 0) { AS[r] = s1; AD[r] = s2; }
}

// ---------- register-tiled f32 GEMM: H = X @ W ----------
// tile 128 rows x 64 cols, BK=32, 256 threads, 8x4 micro-tile per thread
#define BM 128
#define BN 64
#define BK 32
#define XPAD 132
__global__ __launch_bounds__(256) void gemm_f32(
    const float* __restrict__ X, const float* __restrict__ W,
    float* __restrict__ H)
{
    __shared__ float Xs[BK][XPAD];   // [k][row], padded for bank-free b128 reads
    __shared__ float Ws[BK][BN];     // [k][col]
    int t  = threadIdx.x;
    int tx = t & 15;                 // col group: cols tx*4 .. tx*4+3
    int ty = t >> 4;                 // row group: rows ty*8 .. ty*8+7
    int rb = (int)(blockIdx.x >> 1) * BM;
    int cb = (int)(blockIdx.x & 1) * BN;

    float4 acc[8];
    #pragma unroll
    for (int i = 0; i < 8; ++i) acc[i] = {0.f, 0.f, 0.f, 0.f};

    int xr = t >> 3;                 // 0..31: row-in-group for X staging
    int xk = (t & 7) * 4;            // k offset for X staging
    int wr = t >> 4;                 // 0..15: k row for W staging
    int wc = tx * 4;

    for (int k0 = 0; k0 < D; k0 += BK) {
        // stage X tile (transposed into Xs[k][row])
        #pragma unroll
        for (int i = 0; i < 4; ++i) {
            int r = rb + i * 32 + xr;
            float4 v = {0.f, 0.f, 0.f, 0.f};
            if (r < NN) v = *reinterpret_cast<const float4*>(X + (size_t)r * D + k0 + xk);
            Xs[xk + 0][i * 32 + xr] = v.x;
            Xs[xk + 1][i * 32 + xr] = v.y;
            Xs[xk + 2][i * 32 + xr] = v.z;
            Xs[xk + 3][i * 32 + xr] = v.w;
        }
        // stage W tile (rows k0..k0+31, cols cb..cb+63)
        #pragma unroll
        for (int i = 0; i < 2; ++i) {
            int k = i * 16 + wr;
            float4 v = *reinterpret_cast<const float4*>(W + (size_t)(k0 + k) * D + cb + wc);
            *reinterpret_cast<float4*>(&Ws[k][wc]) = v;
        }
        __syncthreads();
        #pragma unroll 8
        for (int kk = 0; kk < BK; ++kk) {
            float4 wv = *reinterpret_cast<const float4*>(&Ws[kk][tx * 4]);
            float4 xa = *reinterpret_cast<const float4*>(&Xs[kk][ty * 8]);
            float4 xb = *reinterpret_cast<const float4*>(&Xs[kk][ty * 8 + 4]);
            acc[0].x += xa.x * wv.x; acc[0].y += xa.x * wv.y; acc[0].z += xa.x * wv.z; acc[0].w += xa.x * wv.w;
            acc[1].x += xa.y * wv.x; acc[1].y += xa.y * wv.y; acc[1].z += xa.y * wv.z; acc[1].w += xa.y * wv.w;
            acc[2].x += xa.z * wv.x; acc[2].y += xa.z * wv.y; acc[2].z += xa.z * wv.z; acc[2].w += xa.z * wv.w;
            acc[3].x += xa.w * wv.x; acc[3].y += xa.w * wv.y; acc[3].z += xa.w * wv.z; acc[3].w += xa.w * wv.w;
            acc[4].x += xb.x * wv.x; acc[4].y += xb.x * wv.y; acc[4].z += xb.x * wv.z; acc[4].w += xb.x * wv.w;
            acc[5].x += xb.y * wv.x; acc[5].y += xb.y * wv.y; acc[5].z += xb.y * wv.z; acc[5].w += xb.y * wv.w;
            acc[6].x += xb.z * wv.x; acc[6].y += xb.z * wv.y; acc[6].z += xb.z * wv.z; acc[6].w += xb.z * wv.w;
            acc[7].x += xb.w * wv.x; acc[7].y += xb.w * wv.y; acc[7].z += xb.w * wv.z; acc[7].w += xb.w * wv.w;
        }
        __syncthreads();
    }
    #pragma unroll
    for (int i = 0; i < 8; ++i) {
        int r = rb + ty * 8 + i;
        if (r < NN)
            *reinterpret_cast<float4*>(H + (size_t)r * D + cb + tx * 4) = acc[i];
    }
}

// ---------- fused per-node: online softmax + gather + bias + relu + pool ----
__global__ __launch_bounds__(256) void gat_node(
    const int* __restrict__ ptr, const int* __restrict__ csr_src,
    const float* __restrict__ AS, const float* __restrict__ AD,
    const float* __restrict__ H, const float* __restrict__ B,
    const int* __restrict__ batch, float* __restrict__ HOUT,
    float* __restrict__ ESUM)
{
    int nid  = (int)((blockIdx.x * blockDim.x + threadIdx.x) >> 6);
    int lane = threadIdx.x & 63;
    if (nid >= NN) return;

    int beg = ptr[nid], end = ptr[nid + 1];
    float ad_d = AD[nid];

    float m = -3.0e38f, den = 0.f, a0 = 0.f, a1 = 0.f;
    int s = csr_src[beg];
    for (int j = beg; j < end; ++j) {
        int snext = (j + 1 < end) ? csr_src[j + 1] : 0;
        float e = AS[s] + ad_d;
        e = e > 0.f ? e : e * NEG_SLOPE;
        float mn = fmaxf(m, e);
        float f = __expf(m - mn);
        float w = __expf(e - mn);
        const float* hs = H + (size_t)s * D;
        float h0 = hs[lane], h1 = hs[lane + 64];
        den = den * f + w;
        a0  = a0  * f + w * h0;
        a1  = a1  * f + w * h1;
        m = mn;
        s = snext;
    }
    float inv = 1.0f / den;
    float o0 = fmaxf(a0 * inv + B[lane],      0.f);
    float o1 = fmaxf(a1 * inv + B[lane + 64], 0.f);
    HOUT[(size_t)nid * D + lane]      = o0;
    HOUT[(size_t)nid * D + lane + 64] = o1;
    int g = batch[nid];
    atomicAdd(ESUM + (size_t)g * D + lane,      o0);
    atomicAdd(ESUM + (size_t)g * D + lane + 64, o1);
}

// ---------- final divide ----------
__global__ void pool_div(const float* __restrict__ ESUM, const float* __restrict__ CNT,
                         float* __restrict__ OUT)
{
    int idx = blockIdx.x * blockDim.x + threadIdx.x;
    if (idx >= NG * D) return;
    int g = idx >> 7;
    float cnt = CNT[g];
    cnt = cnt > 1.f ? cnt : 1.f;
    OUT[idx] = ESUM[idx] / cnt;
}

extern "C" void kernel_launch(void* const* d_in, const int* in_sizes, int n_in,
                              void* d_out, int out_size, void* d_ws, size_t ws_size,
                              hipStream_t stream)
{
    const float* x     = (const float*)d_in[0];
    const int*   ei    = (const int*)d_in[1];
    const int*   batch = (const int*)d_in[2];
    const float* W[2]    = { (const float*)d_in[3], (const float*)d_in[7] };
    const float* ASV[2]  = { (const float*)d_in[4], (const float*)d_in[8] };
    const float* ADV[2]  = { (const float*)d_in[5], (const float*)d_in[9] };
    const float* BV[2]   = { (const float*)d_in[6], (const float*)d_in[10] };
    float* out = (float*)d_out;
    float* ws  = (float*)d_ws;

    const int* ei0 = ei;
    const int* ei1 = ei + NE;

    const int NB = (NN + 255) / 256;

    // ---- workspace layout (32-bit words) ----
    size_t o = 0;
    unsigned* deg   = (unsigned*)(ws + o); o += NN;
    float*    cnt   = ws + o;              o += NG;
    float*    esum0 = ws + o;              o += (size_t)NG * D;
    float*    esum1 = ws + o;              o += (size_t)NG * D;
    const size_t zero_words = o;

    float*    hbuf  = ws + o;              o += (size_t)NN * D;
    float*    hout  = ws + o;              o += (size_t)NN * D;
    float*    asb   = ws + o;              o += NN;
    float*    adb   = ws + o;              o += NN;
    unsigned* chunk = (unsigned*)(ws + o); o += NN;
    int*      ptr   = (int*)(ws + o);      o += NN + 1;
    int*      fill  = (int*)(ws + o);      o += NN;
    int*      csr   = (int*)(ws + o);      o += NT;
    unsigned* parts = (unsigned*)(ws + o); o += 256;
    float*    wv1s  = ws + o;              o += D;
    float*    wv1d  = ws + o;              o += D;
    float*    wv2s  = ws + o;              o += D;
    float*    wv2d  = ws + o;              o += D;

    const int edge_blocks = (NT + 255) / 256;
    const int gemm_blocks = ((NN + BM - 1) / BM) * 2;   // x2 col-halves
    const int gat_blocks  = (NN + 3) / 4;
    const int rd_blocks   = (NN + 3) / 4;
    const int pd_blocks   = (NG * D + 255) / 256;

    // ---- one-time graph prep ----
    zero_kernel<<<256, 256, 0, stream>>>((float4*)ws, (int)(zero_words / 4));
    hist_kernel<<<edge_blocks, 256, 0, stream>>>(ei1, deg);
    cnt_kernel<<<NB, 256, 0, stream>>>(batch, cnt);
    wvec_kernel<<<1, 128, 0, stream>>>(W[0], ASV[0], ADV[0], wv1s, wv1d);
    wvec_kernel<<<1, 128, 0, stream>>>(W[1], ASV[1], ADV[1], wv2s, wv2d);
    scan1<<<NB, 256, 0, stream>>>(deg, chunk, parts);
    scan2<<<1, 256, 0, stream>>>(parts, NB);
    scan3<<<NB, 256, 0, stream>>>(chunk, deg, parts, ptr, fill);
    scatter_kernel<<<edge_blocks, 256, 0, stream>>>(ei0, ei1, fill, csr);

    // ---- layer 1 ----
    row_dots<<<rd_blocks, 256, 0, stream>>>(x, wv1s, wv1d, asb, adb);
    gemm_f32<<<gemm_blocks, 256, 0, stream>>>(x, W[0], hbuf);
    gat_node<<<gat_blocks, 256, 0, stream>>>(ptr, csr, asb, adb, hbuf, BV[0], batch,
                                             hout, esum0);
    pool_div<<<pd_blocks, 256, 0, stream>>>(esum0, cnt, out);

    // ---- layer 2 ----
    row_dots<<<rd_blocks, 256, 0, stream>>>(hout, wv2s, wv2d, asb, adb);
    gemm_f32<<<gemm_blocks, 256, 0, stream>>>(hout, W[1], hbuf);
    gat_node<<<gat_blocks, 256, 0, stream>>>(ptr, csr, asb, adb, hbuf, BV[1], batch,
                                             hout, esum1);
    pool_div<<<pd_blocks, 256, 0, stream>>>(esum1, cnt, out + (size_t)NG * D);
}

// Round 4
// 324.361 us; speedup vs baseline: 3.5278x; 1.0743x over previous
//
#include <hip/hip_runtime.h>
#include <cstdint>
#include <cstddef>

#define NN 50000
#define NE 600000
#define NT (NE + NN)          // 650000 edges incl. self loops
#define NG 1024
#define D 128
#define NEG_SLOPE 0.2f

// ---------- zero a float4 region ----------
__global__ void zero_kernel(float4* __restrict__ p, int n4) {
    int i = blockIdx.x * blockDim.x + threadIdx.x;
    int stride = gridDim.x * blockDim.x;
    float4 z = {0.f, 0.f, 0.f, 0.f};
    for (; i < n4; i += stride) p[i] = z;
}

// ---------- CSR build: histogram of dst ----------
__global__ void hist_kernel(const int* __restrict__ ei1, unsigned* __restrict__ deg) {
    int e = blockIdx.x * blockDim.x + threadIdx.x;
    if (e >= NT) return;
    int d = (e < NE) ? ei1[e] : (e - NE);
    atomicAdd(deg + d, 1u);
}

// ---------- scan pass 1 ----------
__global__ void scan1(const unsigned* __restrict__ deg, unsigned* __restrict__ chunk,
                      unsigned* __restrict__ partials) {
    __shared__ unsigned sm[256];
    int i = blockIdx.x * 256 + threadIdx.x;
    unsigned v = (i < NN) ? deg[i] : 0u;
    sm[threadIdx.x] = v;
    __syncthreads();
    for (int off = 1; off < 256; off <<= 1) {
        unsigned t = (threadIdx.x >= off) ? sm[threadIdx.x - off] : 0u;
        __syncthreads();
        sm[threadIdx.x] += t;
        __syncthreads();
    }
    if (i < NN) chunk[i] = sm[threadIdx.x];
    if (threadIdx.x == 255) partials[blockIdx.x] = sm[255];
}

// ---------- scan pass 2 ----------
__global__ void scan2(unsigned* __restrict__ partials, int nb) {
    __shared__ unsigned sm[256];
    int i = threadIdx.x;
    sm[i] = (i < nb) ? partials[i] : 0u;
    __syncthreads();
    for (int off = 1; off < 256; off <<= 1) {
        unsigned t = (i >= off) ? sm[i - off] : 0u;
        __syncthreads();
        sm[i] += t;
        __syncthreads();
    }
    if (i < nb) partials[i] = sm[i];
}

// ---------- scan pass 3 ----------
__global__ void scan3(const unsigned* __restrict__ chunk, const unsigned* __restrict__ deg,
                      const unsigned* __restrict__ pscan, int* __restrict__ ptr,
                      int* __restrict__ fill) {
    int i = blockIdx.x * 256 + threadIdx.x;
    if (i < NN) {
        unsigned off = blockIdx.x ? pscan[blockIdx.x - 1] : 0u;
        int excl = (int)(chunk[i] - deg[i] + off);
        ptr[i] = excl;
        fill[i] = excl;
    }
    if (i == 0) ptr[NN] = NT;
}

// ---------- CSR build: scatter src indices ----------
__global__ void scatter_kernel(const int* __restrict__ ei0, const int* __restrict__ ei1,
                               int* __restrict__ fill, int* __restrict__ csr_src) {
    int e = blockIdx.x * blockDim.x + threadIdx.x;
    if (e >= NT) return;
    int s, d;
    if (e < NE) { s = ei0[e]; d = ei1[e]; } else { s = d = e - NE; }
    int pos = atomicAdd(fill + d, 1);
    csr_src[pos] = s;
}

// ---------- per-graph node counts ----------
__global__ void cnt_kernel(const int* __restrict__ batch, float* __restrict__ cnt) {
    int r = blockIdx.x * blockDim.x + threadIdx.x;
    if (r >= NN) return;
    atomicAdd(cnt + batch[r], 1.0f);
}

// ---------- tiny: wsv = W @ a_src, wdv = W @ a_dst ----------
__global__ void wvec_kernel(const float* __restrict__ W, const float* __restrict__ a_s,
                            const float* __restrict__ a_d,
                            float* __restrict__ wsv, float* __restrict__ wdv) {
    int k = threadIdx.x;
    if (k >= D) return;
    float s1 = 0.f, s2 = 0.f;
    for (int c = 0; c < D; c += 4) {
        float4 w   = *reinterpret_cast<const float4*>(W + (size_t)k * D + c);
        float4 as4 = *reinterpret_cast<const float4*>(a_s + c);
        float4 ad4 = *reinterpret_cast<const float4*>(a_d + c);
        s1 += w.x * as4.x + w.y * as4.y + w.z * as4.z + w.w * as4.w;
        s2 += w.x * ad4.x + w.y * ad4.y + w.z * ad4.z + w.w * ad4.w;
    }
    wsv[k] = s1; wdv[k] = s2;
}

// ---------- AS[r] = X[r]·wsv, AD[r] = X[r]·wdv  (one wave per row) ----------
__global__ __launch_bounds__(256) void row_dots(
    const float* __restrict__ X, const float* __restrict__ wsv,
    const float* __restrict__ wdv, float* __restrict__ AS, float* __restrict__ AD)
{
    int r = blockIdx.x * 4 + (threadIdx.x >> 6);
    int lane = threadIdx.x & 63;
    if (r >= NN) return;
    float2 x  = *reinterpret_cast<const float2*>(X + (size_t)r * D + lane * 2);
    float2 ws = *reinterpret_cast<const float2*>(wsv + lane * 2);
    float2 wd = *reinterpret_cast<const float2*>(wdv + lane * 2);
    float s1 = x.x * ws.x + x.y * ws.y;
    float s2 = x.x * wd.x + x.y * wd.y;
    #pragma unroll
    for (int off = 32; off; off >>= 1) {
        s1 += __shfl_down(s1, off, 64);
        s2 += __shfl_down(s2, off, 64);
    }
    if (lane == 0) { AS[r] = s1; AD[r] = s2; }
}

// ---------- register-tiled f32 GEMM: H = X @ W ----------
#define BM 128
#define BN 64
#define BK 32
#define XPAD 132
__global__ __launch_bounds__(256) void gemm_f32(
    const float* __restrict__ X, const float* __restrict__ W,
    float* __restrict__ H)
{
    __shared__ float Xs[BK][XPAD];
    __shared__ float Ws[BK][BN];
    int t  = threadIdx.x;
    int tx = t & 15;
    int ty = t >> 4;
    int rb = (int)(blockIdx.x >> 1) * BM;
    int cb = (int)(blockIdx.x & 1) * BN;

    float4 acc[8];
    #pragma unroll
    for (int i = 0; i < 8; ++i) acc[i] = {0.f, 0.f, 0.f, 0.f};

    int xr = t >> 3;
    int xk = (t & 7) * 4;
    int wr = t >> 4;
    int wc = tx * 4;

    for (int k0 = 0; k0 < D; k0 += BK) {
        #pragma unroll
        for (int i = 0; i < 4; ++i) {
            int r = rb + i * 32 + xr;
            float4 v = {0.f, 0.f, 0.f, 0.f};
            if (r < NN) v = *reinterpret_cast<const float4*>(X + (size_t)r * D + k0 + xk);
            Xs[xk + 0][i * 32 + xr] = v.x;
            Xs[xk + 1][i * 32 + xr] = v.y;
            Xs[xk + 2][i * 32 + xr] = v.z;
            Xs[xk + 3][i * 32 + xr] = v.w;
        }
        #pragma unroll
        for (int i = 0; i < 2; ++i) {
            int k = i * 16 + wr;
            float4 v = *reinterpret_cast<const float4*>(W + (size_t)(k0 + k) * D + cb + wc);
            *reinterpret_cast<float4*>(&Ws[k][wc]) = v;
        }
        __syncthreads();
        #pragma unroll 8
        for (int kk = 0; kk < BK; ++kk) {
            float4 wv = *reinterpret_cast<const float4*>(&Ws[kk][tx * 4]);
            float4 xa = *reinterpret_cast<const float4*>(&Xs[kk][ty * 8]);
            float4 xb = *reinterpret_cast<const float4*>(&Xs[kk][ty * 8 + 4]);
            acc[0].x += xa.x * wv.x; acc[0].y += xa.x * wv.y; acc[0].z += xa.x * wv.z; acc[0].w += xa.x * wv.w;
            acc[1].x += xa.y * wv.x; acc[1].y += xa.y * wv.y; acc[1].z += xa.y * wv.z; acc[1].w += xa.y * wv.w;
            acc[2].x += xa.z * wv.x; acc[2].y += xa.z * wv.y; acc[2].z += xa.z * wv.z; acc[2].w += xa.z * wv.w;
            acc[3].x += xa.w * wv.x; acc[3].y += xa.w * wv.y; acc[3].z += xa.w * wv.z; acc[3].w += xa.w * wv.w;
            acc[4].x += xb.x * wv.x; acc[4].y += xb.x * wv.y; acc[4].z += xb.x * wv.z; acc[4].w += xb.x * wv.w;
            acc[5].x += xb.y * wv.x; acc[5].y += xb.y * wv.y; acc[5].z += xb.y * wv.z; acc[5].w += xb.y * wv.w;
            acc[6].x += xb.z * wv.x; acc[6].y += xb.z * wv.y; acc[6].z += xb.z * wv.z; acc[6].w += xb.z * wv.w;
            acc[7].x += xb.w * wv.x; acc[7].y += xb.w * wv.y; acc[7].z += xb.w * wv.z; acc[7].w += xb.w * wv.w;
        }
        __syncthreads();
    }
    #pragma unroll
    for (int i = 0; i < 8; ++i) {
        int r = rb + ty * 8 + i;
        if (r < NN)
            *reinterpret_cast<float4*>(H + (size_t)r * D + cb + tx * 4) = acc[i];
    }
}

// ---------- fused per-node GAT: two-phase (lane-parallel softmax, then
//            broadcast-weighted gather with 8-deep MLP). One wave/node. ------
__device__ __forceinline__ float readlane_f(float v, int l) {
    return __int_as_float(__builtin_amdgcn_readlane(__float_as_int(v), l));
}

__global__ __launch_bounds__(256) void gat_node(
    const int* __restrict__ ptr, const int* __restrict__ csr_src,
    const float* __restrict__ AS, const float* __restrict__ AD,
    const float* __restrict__ H, const float* __restrict__ B,
    const int* __restrict__ batch, float* __restrict__ HOUT,
    float* __restrict__ ESUM)
{
    int nid  = (int)((blockIdx.x * blockDim.x + threadIdx.x) >> 6);
    int lane = threadIdx.x & 63;
    if (nid >= NN) return;

    int beg = ptr[nid], end = ptr[nid + 1];
    int deg = end - beg;
    float ad_d = AD[nid];

    float m = -3.0e38f, den = 0.f;
    float hx = 0.f, hy = 0.f;
    const float* hb = H + (size_t)lane * 2;

    for (int c0 = 0; c0 < deg; c0 += 64) {
        int cnt = deg - c0; if (cnt > 64) cnt = 64;

        // ---- phase 1: lane-parallel scores + wave softmax ----
        int   s_l = 0;
        float e_l = -3.0e38f;
        if (lane < cnt) {
            s_l = csr_src[beg + c0 + lane];
            float e = AS[s_l] + ad_d;
            e_l = e > 0.f ? e : e * NEG_SLOPE;
        }
        float cm = e_l;
        #pragma unroll
        for (int off = 32; off; off >>= 1)
            cm = fmaxf(cm, __shfl_xor(cm, off, 64));
        float mn = fmaxf(m, cm);
        float w_l = (lane < cnt) ? __expf(e_l - mn) : 0.f;
        float cs = w_l;
        #pragma unroll
        for (int off = 32; off; off >>= 1)
            cs += __shfl_xor(cs, off, 64);
        float f = __expf(m - mn);
        den = den * f + cs;
        hx *= f; hy *= f;
        m = mn;

        // ---- phase 2: broadcast-weighted gather, 8 loads in flight ----
        int j = 0;
        for (; j + 8 <= cnt; j += 8) {
            int   s0 = __builtin_amdgcn_readlane(s_l, j);
            int   s1 = __builtin_amdgcn_readlane(s_l, j + 1);
            int   s2 = __builtin_amdgcn_readlane(s_l, j + 2);
            int   s3 = __builtin_amdgcn_readlane(s_l, j + 3);
            int   s4 = __builtin_amdgcn_readlane(s_l, j + 4);
            int   s5 = __builtin_amdgcn_readlane(s_l, j + 5);
            int   s6 = __builtin_amdgcn_readlane(s_l, j + 6);
            int   s7 = __builtin_amdgcn_readlane(s_l, j + 7);
            float w0 = readlane_f(w_l, j);
            float w1 = readlane_f(w_l, j + 1);
            float w2 = readlane_f(w_l, j + 2);
            float w3 = readlane_f(w_l, j + 3);
            float w4 = readlane_f(w_l, j + 4);
            float w5 = readlane_f(w_l, j + 5);
            float w6 = readlane_f(w_l, j + 6);
            float w7 = readlane_f(w_l, j + 7);
            float2 h0 = *reinterpret_cast<const float2*>(hb + (size_t)s0 * D);
            float2 h1 = *reinterpret_cast<const float2*>(hb + (size_t)s1 * D);
            float2 h2 = *reinterpret_cast<const float2*>(hb + (size_t)s2 * D);
            float2 h3 = *reinterpret_cast<const float2*>(hb + (size_t)s3 * D);
            float2 h4 = *reinterpret_cast<const float2*>(hb + (size_t)s4 * D);
            float2 h5 = *reinterpret_cast<const float2*>(hb + (size_t)s5 * D);
            float2 h6 = *reinterpret_cast<const float2*>(hb + (size_t)s6 * D);
            float2 h7 = *reinterpret_cast<const float2*>(hb + (size_t)s7 * D);
            hx += w0 * h0.x; hy += w0 * h0.y;
            hx += w1 * h1.x; hy += w1 * h1.y;
            hx += w2 * h2.x; hy += w2 * h2.y;
            hx += w3 * h3.x; hy += w3 * h3.y;
            hx += w4 * h4.x; hy += w4 * h4.y;
            hx += w5 * h5.x; hy += w5 * h5.y;
            hx += w6 * h6.x; hy += w6 * h6.y;
            hx += w7 * h7.x; hy += w7 * h7.y;
        }
        for (; j + 4 <= cnt; j += 4) {
            int   s0 = __builtin_amdgcn_readlane(s_l, j);
            int   s1 = __builtin_amdgcn_readlane(s_l, j + 1);
            int   s2 = __builtin_amdgcn_readlane(s_l, j + 2);
            int   s3 = __builtin_amdgcn_readlane(s_l, j + 3);
            float w0 = readlane_f(w_l, j);
            float w1 = readlane_f(w_l, j + 1);
            float w2 = readlane_f(w_l, j + 2);
            float w3 = readlane_f(w_l, j + 3);
            float2 h0 = *reinterpret_cast<const float2*>(hb + (size_t)s0 * D);
            float2 h1 = *reinterpret_cast<const float2*>(hb + (size_t)s1 * D);
            float2 h2 = *reinterpret_cast<const float2*>(hb + (size_t)s2 * D);
            float2 h3 = *reinterpret_cast<const float2*>(hb + (size_t)s3 * D);
            hx += w0 * h0.x; hy += w0 * h0.y;
            hx += w1 * h1.x; hy += w1 * h1.y;
            hx += w2 * h2.x; hy += w2 * h2.y;
            hx += w3 * h3.x; hy += w3 * h3.y;
        }
        for (; j < cnt; ++j) {
            int   s0 = __builtin_amdgcn_readlane(s_l, j);
            float w0 = readlane_f(w_l, j);
            float2 h0 = *reinterpret_cast<const float2*>(hb + (size_t)s0 * D);
            hx += w0 * h0.x; hy += w0 * h0.y;
        }
    }

    float inv = 1.0f / den;
    float2 bv = *reinterpret_cast<const float2*>(B + lane * 2);
    float ox = fmaxf(hx * inv + bv.x, 0.f);
    float oy = fmaxf(hy * inv + bv.y, 0.f);
    *reinterpret_cast<float2*>(HOUT + (size_t)nid * D + lane * 2) = {ox, oy};
    int g = batch[nid];
    atomicAdd(ESUM + (size_t)g * D + lane * 2,     ox);
    atomicAdd(ESUM + (size_t)g * D + lane * 2 + 1, oy);
}

// ---------- final divide ----------
__global__ void pool_div(const float* __restrict__ ESUM, const float* __restrict__ CNT,
                         float* __restrict__ OUT)
{
    int idx = blockIdx.x * blockDim.x + threadIdx.x;
    if (idx >= NG * D) return;
    int g = idx >> 7;
    float cnt = CNT[g];
    cnt = cnt > 1.f ? cnt : 1.f;
    OUT[idx] = ESUM[idx] / cnt;
}

extern "C" void kernel_launch(void* const* d_in, const int* in_sizes, int n_in,
                              void* d_out, int out_size, void* d_ws, size_t ws_size,
                              hipStream_t stream)
{
    const float* x     = (const float*)d_in[0];
    const int*   ei    = (const int*)d_in[1];
    const int*   batch = (const int*)d_in[2];
    const float* W[2]    = { (const float*)d_in[3], (const float*)d_in[7] };
    const float* ASV[2]  = { (const float*)d_in[4], (const float*)d_in[8] };
    const float* ADV[2]  = { (const float*)d_in[5], (const float*)d_in[9] };
    const float* BV[2]   = { (const float*)d_in[6], (const float*)d_in[10] };
    float* out = (float*)d_out;
    float* ws  = (float*)d_ws;

    const int* ei0 = ei;
    const int* ei1 = ei + NE;

    const int NB = (NN + 255) / 256;

    // ---- workspace layout (32-bit words) ----
    size_t o = 0;
    unsigned* deg   = (unsigned*)(ws + o); o += NN;
    float*    cnt   = ws + o;              o += NG;
    float*    esum0 = ws + o;              o += (size_t)NG * D;
    float*    esum1 = ws + o;              o += (size_t)NG * D;
    const size_t zero_words = o;

    float*    hbuf  = ws + o;              o += (size_t)NN * D;
    float*    hout  = ws + o;              o += (size_t)NN * D;
    float*    asb   = ws + o;              o += NN;
    float*    adb   = ws + o;              o += NN;
    unsigned* chunk = (unsigned*)(ws + o); o += NN;
    int*      ptr   = (int*)(ws + o);      o += NN + 1;
    int*      fill  = (int*)(ws + o);      o += NN;
    int*      csr   = (int*)(ws + o);      o += NT;
    unsigned* parts = (unsigned*)(ws + o); o += 256;
    float*    wv1s  = ws + o;              o += D;
    float*    wv1d  = ws + o;              o += D;
    float*    wv2s  = ws + o;              o += D;
    float*    wv2d  = ws + o;              o += D;

    const int edge_blocks = (NT + 255) / 256;
    const int gemm_blocks = ((NN + BM - 1) / BM) * 2;
    const int gat_blocks  = (NN + 3) / 4;
    const int rd_blocks   = (NN + 3) / 4;
    const int pd_blocks   = (NG * D + 255) / 256;

    // ---- one-time graph prep ----
    zero_kernel<<<256, 256, 0, stream>>>((float4*)ws, (int)(zero_words / 4));
    hist_kernel<<<edge_blocks, 256, 0, stream>>>(ei1, deg);
    cnt_kernel<<<NB, 256, 0, stream>>>(batch, cnt);
    wvec_kernel<<<1, 128, 0, stream>>>(W[0], ASV[0], ADV[0], wv1s, wv1d);
    wvec_kernel<<<1, 128, 0, stream>>>(W[1], ASV[1], ADV[1], wv2s, wv2d);
    scan1<<<NB, 256, 0, stream>>>(deg, chunk, parts);
    scan2<<<1, 256, 0, stream>>>(parts, NB);
    scan3<<<NB, 256, 0, stream>>>(chunk, deg, parts, ptr, fill);
    scatter_kernel<<<edge_blocks, 256, 0, stream>>>(ei0, ei1, fill, csr);

    // ---- layer 1 ----
    row_dots<<<rd_blocks, 256, 0, stream>>>(x, wv1s, wv1d, asb, adb);
    gemm_f32<<<gemm_blocks, 256, 0, stream>>>(x, W[0], hbuf);
    gat_node<<<gat_blocks, 256, 0, stream>>>(ptr, csr, asb, adb, hbuf, BV[0], batch,
                                             hout, esum0);
    pool_div<<<pd_blocks, 256, 0, stream>>>(esum0, cnt, out);

    // ---- layer 2 ----
    row_dots<<<rd_blocks, 256, 0, stream>>>(hout, wv2s, wv2d, asb, adb);
    gemm_f32<<<gemm_blocks, 256, 0, stream>>>(hout, W[1], hbuf);
    gat_node<<<gat_blocks, 256, 0, stream>>>(ptr, csr, asb, adb, hbuf, BV[1], batch,
                                             hout, esum1);
    pool_div<<<pd_blocks, 256, 0, stream>>>(esum1, cnt, out + (size_t)NG * D);
}

// Round 5
// 295.910 us; speedup vs baseline: 3.8670x; 1.0961x over previous
//
#include <hip/hip_runtime.h>
#include <hip/hip_fp16.h>
#include <cstdint>
#include <cstddef>

#define NN 50000
#define NE 600000
#define NT (NE + NN)          // 650000 edges incl. self loops
#define NG 1024
#define D 128
#define NEG_SLOPE 0.2f

// ---------- zero a float4 region ----------
__global__ void zero_kernel(float4* __restrict__ p, int n4) {
    int i = blockIdx.x * blockDim.x + threadIdx.x;
    int stride = gridDim.x * blockDim.x;
    float4 z = {0.f, 0.f, 0.f, 0.f};
    for (; i < n4; i += stride) p[i] = z;
}

// ---------- prep: dst histogram + per-graph node counts ----------
__global__ void prep_kernel(const int* __restrict__ ei1, const int* __restrict__ batch,
                            unsigned* __restrict__ deg, float* __restrict__ cnt) {
    int e = blockIdx.x * blockDim.x + threadIdx.x;
    if (e < NT) {
        int d = (e < NE) ? ei1[e] : (e - NE);
        atomicAdd(deg + d, 1u);
    }
    if (e < NN) atomicAdd(cnt + batch[e], 1.0f);
}

// ---------- scan pass 1 ----------
__global__ void scan1(const unsigned* __restrict__ deg, unsigned* __restrict__ chunk,
                      unsigned* __restrict__ partials) {
    __shared__ unsigned sm[256];
    int i = blockIdx.x * 256 + threadIdx.x;
    unsigned v = (i < NN) ? deg[i] : 0u;
    sm[threadIdx.x] = v;
    __syncthreads();
    for (int off = 1; off < 256; off <<= 1) {
        unsigned t = (threadIdx.x >= off) ? sm[threadIdx.x - off] : 0u;
        __syncthreads();
        sm[threadIdx.x] += t;
        __syncthreads();
    }
    if (i < NN) chunk[i] = sm[threadIdx.x];
    if (threadIdx.x == 255) partials[blockIdx.x] = sm[255];
}

// ---------- scan pass 2 ----------
__global__ void scan2(unsigned* __restrict__ partials, int nb) {
    __shared__ unsigned sm[256];
    int i = threadIdx.x;
    sm[i] = (i < nb) ? partials[i] : 0u;
    __syncthreads();
    for (int off = 1; off < 256; off <<= 1) {
        unsigned t = (i >= off) ? sm[i - off] : 0u;
        __syncthreads();
        sm[i] += t;
        __syncthreads();
    }
    if (i < nb) partials[i] = sm[i];
}

// ---------- scan pass 3 ----------
__global__ void scan3(const unsigned* __restrict__ chunk, const unsigned* __restrict__ deg,
                      const unsigned* __restrict__ pscan, int* __restrict__ ptr,
                      int* __restrict__ fill) {
    int i = blockIdx.x * 256 + threadIdx.x;
    if (i < NN) {
        unsigned off = blockIdx.x ? pscan[blockIdx.x - 1] : 0u;
        int excl = (int)(chunk[i] - deg[i] + off);
        ptr[i] = excl;
        fill[i] = excl;
    }
    if (i == 0) ptr[NN] = NT;
}

// ---------- CSR build: scatter src indices ----------
__global__ void scatter_kernel(const int* __restrict__ ei0, const int* __restrict__ ei1,
                               int* __restrict__ fill, int* __restrict__ csr_src) {
    int e = blockIdx.x * blockDim.x + threadIdx.x;
    if (e >= NT) return;
    int s, d;
    if (e < NE) { s = ei0[e]; d = ei1[e]; } else { s = d = e - NE; }
    int pos = atomicAdd(fill + d, 1);
    csr_src[pos] = s;
}

// ---------- fused GEMM: Hh(fp16) = X @ W; ASP/ADP partial alpha dots --------
// tile 128 rows x 64 cols, BK=32, 256 threads, 8x4 micro-tile per thread
#define BM 128
#define BN 64
#define BK 32
#define XPAD 132
__global__ __launch_bounds__(256) void gemm_fused(
    const float* __restrict__ X, const float* __restrict__ W,
    const float* __restrict__ a_s, const float* __restrict__ a_d,
    __half2* __restrict__ Hh, float* __restrict__ ASP, float* __restrict__ ADP)
{
    __shared__ float Xs[BK][XPAD];   // [k][row] transposed
    __shared__ float Ws[BK][BN];     // [k][col]
    int t  = threadIdx.x;
    int tx = t & 15;
    int ty = t >> 4;
    int rb = (int)(blockIdx.x >> 1) * BM;
    int cb = (int)(blockIdx.x & 1);          // 0 or 1 (col half)
    int c0 = cb * BN;

    float4 acc[8];
    #pragma unroll
    for (int i = 0; i < 8; ++i) acc[i] = {0.f, 0.f, 0.f, 0.f};

    int xr = t >> 3;
    int xk = (t & 7) * 4;
    int wr = t >> 4;
    int wc = tx * 4;

    for (int k0 = 0; k0 < D; k0 += BK) {
        #pragma unroll
        for (int i = 0; i < 4; ++i) {
            int r = rb + i * 32 + xr;
            float4 v = {0.f, 0.f, 0.f, 0.f};
            if (r < NN) v = *reinterpret_cast<const float4*>(X + (size_t)r * D + k0 + xk);
            Xs[xk + 0][i * 32 + xr] = v.x;
            Xs[xk + 1][i * 32 + xr] = v.y;
            Xs[xk + 2][i * 32 + xr] = v.z;
            Xs[xk + 3][i * 32 + xr] = v.w;
        }
        #pragma unroll
        for (int i = 0; i < 2; ++i) {
            int k = i * 16 + wr;
            float4 v = *reinterpret_cast<const float4*>(W + (size_t)(k0 + k) * D + c0 + wc);
            *reinterpret_cast<float4*>(&Ws[k][wc]) = v;
        }
        __syncthreads();
        #pragma unroll 8
        for (int kk = 0; kk < BK; ++kk) {
            float4 wv = *reinterpret_cast<const float4*>(&Ws[kk][tx * 4]);
            float4 xa = *reinterpret_cast<const float4*>(&Xs[kk][ty * 8]);
            float4 xb = *reinterpret_cast<const float4*>(&Xs[kk][ty * 8 + 4]);
            acc[0].x += xa.x * wv.x; acc[0].y += xa.x * wv.y; acc[0].z += xa.x * wv.z; acc[0].w += xa.x * wv.w;
            acc[1].x += xa.y * wv.x; acc[1].y += xa.y * wv.y; acc[1].z += xa.y * wv.z; acc[1].w += xa.y * wv.w;
            acc[2].x += xa.z * wv.x; acc[2].y += xa.z * wv.y; acc[2].z += xa.z * wv.z; acc[2].w += xa.z * wv.w;
            acc[3].x += xa.w * wv.x; acc[3].y += xa.w * wv.y; acc[3].z += xa.w * wv.z; acc[3].w += xa.w * wv.w;
            acc[4].x += xb.x * wv.x; acc[4].y += xb.x * wv.y; acc[4].z += xb.x * wv.z; acc[4].w += xb.x * wv.w;
            acc[5].x += xb.y * wv.x; acc[5].y += xb.y * wv.y; acc[5].z += xb.y * wv.z; acc[5].w += xb.y * wv.w;
            acc[6].x += xb.z * wv.x; acc[6].y += xb.z * wv.y; acc[6].z += xb.z * wv.z; acc[6].w += xb.z * wv.w;
            acc[7].x += xb.w * wv.x; acc[7].y += xb.w * wv.y; acc[7].z += xb.w * wv.z; acc[7].w += xb.w * wv.w;
        }
        __syncthreads();
    }

    // epilogue: fp16 H store + alpha partial dots (reduced over the 16 tx lanes)
    float4 av_s = *reinterpret_cast<const float4*>(a_s + c0 + tx * 4);
    float4 av_d = *reinterpret_cast<const float4*>(a_d + c0 + tx * 4);
    #pragma unroll
    for (int i = 0; i < 8; ++i) {
        int r = rb + ty * 8 + i;
        float s1 = acc[i].x * av_s.x + acc[i].y * av_s.y + acc[i].z * av_s.z + acc[i].w * av_s.w;
        float s2 = acc[i].x * av_d.x + acc[i].y * av_d.y + acc[i].z * av_d.z + acc[i].w * av_d.w;
        #pragma unroll
        for (int off = 8; off; off >>= 1) {
            s1 += __shfl_xor(s1, off, 64);
            s2 += __shfl_xor(s2, off, 64);
        }
        if (r < NN) {
            __half2 p0 = __floats2half2_rn(acc[i].x, acc[i].y);
            __half2 p1 = __floats2half2_rn(acc[i].z, acc[i].w);
            __half2* rowp = Hh + (size_t)r * 64 + c0 / 2 + tx * 2;
            rowp[0] = p0;
            rowp[1] = p1;
            if (tx == 0) {
                ASP[2 * (size_t)r + cb] = s1;
                ADP[2 * (size_t)r + cb] = s2;
            }
        }
    }
}

// ---------- fused per-node GAT: two-phase, fp16 gather. One wave/node. ------
__device__ __forceinline__ float readlane_f(float v, int l) {
    return __int_as_float(__builtin_amdgcn_readlane(__float_as_int(v), l));
}

__global__ __launch_bounds__(256) void gat_node(
    const int* __restrict__ ptr, const int* __restrict__ csr_src,
    const float* __restrict__ ASP, const float* __restrict__ ADP,
    const __half2* __restrict__ Hh, const float* __restrict__ B,
    const int* __restrict__ batch, float* __restrict__ HOUT,
    float* __restrict__ ESUM)
{
    int nid  = (int)((blockIdx.x * blockDim.x + threadIdx.x) >> 6);
    int lane = threadIdx.x & 63;
    if (nid >= NN) return;

    int beg = ptr[nid], end = ptr[nid + 1];
    int deg = end - beg;
    float2 adp = *reinterpret_cast<const float2*>(ADP + 2 * (size_t)nid);
    float ad_d = adp.x + adp.y;

    float m = -3.0e38f, den = 0.f;
    float hx = 0.f, hy = 0.f;
    const __half2* hb = Hh + lane;       // row stride = 64 half2

    for (int c0 = 0; c0 < deg; c0 += 64) {
        int cnt = deg - c0; if (cnt > 64) cnt = 64;

        // ---- phase 1: lane-parallel scores + wave softmax ----
        int   s_l = 0;
        float e_l = -3.0e38f;
        if (lane < cnt) {
            s_l = csr_src[beg + c0 + lane];
            float2 asp = *reinterpret_cast<const float2*>(ASP + 2 * (size_t)s_l);
            float e = asp.x + asp.y + ad_d;
            e_l = e > 0.f ? e : e * NEG_SLOPE;
        }
        float cm = e_l;
        #pragma unroll
        for (int off = 32; off; off >>= 1)
            cm = fmaxf(cm, __shfl_xor(cm, off, 64));
        float mn = fmaxf(m, cm);
        float w_l = (lane < cnt) ? __expf(e_l - mn) : 0.f;
        float cs = w_l;
        #pragma unroll
        for (int off = 32; off; off >>= 1)
            cs += __shfl_xor(cs, off, 64);
        float f = __expf(m - mn);
        den = den * f + cs;
        hx *= f; hy *= f;
        m = mn;

        // ---- phase 2: broadcast-weighted fp16 gather, 8 loads in flight ----
        int j = 0;
        for (; j + 8 <= cnt; j += 8) {
            int   s0 = __builtin_amdgcn_readlane(s_l, j);
            int   s1 = __builtin_amdgcn_readlane(s_l, j + 1);
            int   s2 = __builtin_amdgcn_readlane(s_l, j + 2);
            int   s3 = __builtin_amdgcn_readlane(s_l, j + 3);
            int   s4 = __builtin_amdgcn_readlane(s_l, j + 4);
            int   s5 = __builtin_amdgcn_readlane(s_l, j + 5);
            int   s6 = __builtin_amdgcn_readlane(s_l, j + 6);
            int   s7 = __builtin_amdgcn_readlane(s_l, j + 7);
            float w0 = readlane_f(w_l, j);
            float w1 = readlane_f(w_l, j + 1);
            float w2 = readlane_f(w_l, j + 2);
            float w3 = readlane_f(w_l, j + 3);
            float w4 = readlane_f(w_l, j + 4);
            float w5 = readlane_f(w_l, j + 5);
            float w6 = readlane_f(w_l, j + 6);
            float w7 = readlane_f(w_l, j + 7);
            float2 h0 = __half22float2(hb[(size_t)s0 * 64]);
            float2 h1 = __half22float2(hb[(size_t)s1 * 64]);
            float2 h2 = __half22float2(hb[(size_t)s2 * 64]);
            float2 h3 = __half22float2(hb[(size_t)s3 * 64]);
            float2 h4 = __half22float2(hb[(size_t)s4 * 64]);
            float2 h5 = __half22float2(hb[(size_t)s5 * 64]);
            float2 h6 = __half22float2(hb[(size_t)s6 * 64]);
            float2 h7 = __half22float2(hb[(size_t)s7 * 64]);
            hx += w0 * h0.x; hy += w0 * h0.y;
            hx += w1 * h1.x; hy += w1 * h1.y;
            hx += w2 * h2.x; hy += w2 * h2.y;
            hx += w3 * h3.x; hy += w3 * h3.y;
            hx += w4 * h4.x; hy += w4 * h4.y;
            hx += w5 * h5.x; hy += w5 * h5.y;
            hx += w6 * h6.x; hy += w6 * h6.y;
            hx += w7 * h7.x; hy += w7 * h7.y;
        }
        for (; j + 4 <= cnt; j += 4) {
            int   s0 = __builtin_amdgcn_readlane(s_l, j);
            int   s1 = __builtin_amdgcn_readlane(s_l, j + 1);
            int   s2 = __builtin_amdgcn_readlane(s_l, j + 2);
            int   s3 = __builtin_amdgcn_readlane(s_l, j + 3);
            float w0 = readlane_f(w_l, j);
            float w1 = readlane_f(w_l, j + 1);
            float w2 = readlane_f(w_l, j + 2);
            float w3 = readlane_f(w_l, j + 3);
            float2 h0 = __half22float2(hb[(size_t)s0 * 64]);
            float2 h1 = __half22float2(hb[(size_t)s1 * 64]);
            float2 h2 = __half22float2(hb[(size_t)s2 * 64]);
            float2 h3 = __half22float2(hb[(size_t)s3 * 64]);
            hx += w0 * h0.x; hy += w0 * h0.y;
            hx += w1 * h1.x; hy += w1 * h1.y;
            hx += w2 * h2.x; hy += w2 * h2.y;
            hx += w3 * h3.x; hy += w3 * h3.y;
        }
        for (; j < cnt; ++j) {
            int   s0 = __builtin_amdgcn_readlane(s_l, j);
            float w0 = readlane_f(w_l, j);
            float2 h0 = __half22float2(hb[(size_t)s0 * 64]);
            hx += w0 * h0.x; hy += w0 * h0.y;
        }
    }

    float inv = 1.0f / den;
    float2 bv = *reinterpret_cast<const float2*>(B + lane * 2);
    float ox = fmaxf(hx * inv + bv.x, 0.f);
    float oy = fmaxf(hy * inv + bv.y, 0.f);
    *reinterpret_cast<float2*>(HOUT + (size_t)nid * D + lane * 2) = {ox, oy};
    int g = batch[nid];
    atomicAdd(ESUM + (size_t)g * D + lane * 2,     ox);
    atomicAdd(ESUM + (size_t)g * D + lane * 2 + 1, oy);
}

// ---------- final divide ----------
__global__ void pool_div(const float* __restrict__ ESUM, const float* __restrict__ CNT,
                         float* __restrict__ OUT)
{
    int idx = blockIdx.x * blockDim.x + threadIdx.x;
    if (idx >= NG * D) return;
    int g = idx >> 7;
    float cnt = CNT[g];
    cnt = cnt > 1.f ? cnt : 1.f;
    OUT[idx] = ESUM[idx] / cnt;
}

extern "C" void kernel_launch(void* const* d_in, const int* in_sizes, int n_in,
                              void* d_out, int out_size, void* d_ws, size_t ws_size,
                              hipStream_t stream)
{
    const float* x     = (const float*)d_in[0];
    const int*   ei    = (const int*)d_in[1];
    const int*   batch = (const int*)d_in[2];
    const float* W[2]    = { (const float*)d_in[3], (const float*)d_in[7] };
    const float* ASV[2]  = { (const float*)d_in[4], (const float*)d_in[8] };
    const float* ADV[2]  = { (const float*)d_in[5], (const float*)d_in[9] };
    const float* BV[2]   = { (const float*)d_in[6], (const float*)d_in[10] };
    float* out = (float*)d_out;
    float* ws  = (float*)d_ws;

    const int* ei0 = ei;
    const int* ei1 = ei + NE;

    const int NB = (NN + 255) / 256;

    // ---- workspace layout (32-bit words) ----
    size_t o = 0;
    unsigned* deg   = (unsigned*)(ws + o); o += NN;
    float*    cnt   = ws + o;              o += NG;
    float*    esum0 = ws + o;              o += (size_t)NG * D;
    float*    esum1 = ws + o;              o += (size_t)NG * D;
    const size_t zero_words = o;                       // 313168 (mult of 4)

    __half2*  Hh    = (__half2*)(ws + o);  o += (size_t)NN * 64;   // fp16 H
    float*    hout  = ws + o;              o += (size_t)NN * D;    // f32 gat out
    float*    asp   = ws + o;              o += 2 * (size_t)NN;
    float*    adp   = ws + o;              o += 2 * (size_t)NN;
    unsigned* chunk = (unsigned*)(ws + o); o += NN;
    int*      ptr   = (int*)(ws + o);      o += NN + 1;
    int*      fill  = (int*)(ws + o);      o += NN;
    int*      csr   = (int*)(ws + o);      o += NT;
    unsigned* parts = (unsigned*)(ws + o); o += 256;

    const int edge_blocks = (NT + 255) / 256;
    const int gemm_blocks = ((NN + BM - 1) / BM) * 2;
    const int gat_blocks  = (NN + 3) / 4;
    const int pd_blocks   = (NG * D + 255) / 256;

    // ---- one-time graph prep ----
    zero_kernel<<<256, 256, 0, stream>>>((float4*)ws, (int)(zero_words / 4));
    prep_kernel<<<edge_blocks, 256, 0, stream>>>(ei1, batch, deg, cnt);
    scan1<<<NB, 256, 0, stream>>>(deg, chunk, parts);
    scan2<<<1, 256, 0, stream>>>(parts, NB);
    scan3<<<NB, 256, 0, stream>>>(chunk, deg, parts, ptr, fill);
    scatter_kernel<<<edge_blocks, 256, 0, stream>>>(ei0, ei1, fill, csr);

    // ---- layer 1 ----
    gemm_fused<<<gemm_blocks, 256, 0, stream>>>(x, W[0], ASV[0], ADV[0], Hh, asp, adp);
    gat_node<<<gat_blocks, 256, 0, stream>>>(ptr, csr, asp, adp, Hh, BV[0], batch,
                                             hout, esum0);
    pool_div<<<pd_blocks, 256, 0, stream>>>(esum0, cnt, out);

    // ---- layer 2 ----
    gemm_fused<<<gemm_blocks, 256, 0, stream>>>(hout, W[1], ASV[1], ADV[1], Hh, asp, adp);
    gat_node<<<gat_blocks, 256, 0, stream>>>(ptr, csr, asp, adp, Hh, BV[1], batch,
                                             hout, esum1);
    pool_div<<<pd_blocks, 256, 0, stream>>>(esum1, cnt, out + (size_t)NG * D);
}

// Round 6
// 215.276 us; speedup vs baseline: 5.3155x; 1.3746x over previous
//
#include <hip/hip_runtime.h>
#include <hip/hip_fp16.h>
#include <cstdint>
#include <cstddef>

#define NN 50000
#define NE 600000
#define NT (NE + NN)          // 650000 edges incl. self loops
#define NG 1024
#define D 128
#define NEG_SLOPE 0.2f

typedef _Float16 half8 __attribute__((ext_vector_type(8)));
typedef float f32x4 __attribute__((ext_vector_type(4)));

// ---------- zero a float4 region ----------
__global__ void zero_kernel(float4* __restrict__ p, int n4) {
    int i = blockIdx.x * blockDim.x + threadIdx.x;
    int stride = gridDim.x * blockDim.x;
    float4 z = {0.f, 0.f, 0.f, 0.f};
    for (; i < n4; i += stride) p[i] = z;
}

// ---------- dst histogram ----------
__global__ void hist_kernel(const int* __restrict__ ei1, unsigned* __restrict__ deg) {
    int e = blockIdx.x * blockDim.x + threadIdx.x;
    if (e >= NT) return;
    int d = (e < NE) ? ei1[e] : (e - NE);
    atomicAdd(deg + d, 1u);
}

// ---------- W -> transposed fp16 (both layers in one launch) ----------
__global__ void wt_kernel(const float* __restrict__ W1, const float* __restrict__ W2,
                          _Float16* __restrict__ Wt1, _Float16* __restrict__ Wt2) {
    int i = blockIdx.x * 256 + threadIdx.x;      // 0..32767
    if (i >= 2 * D * D) return;
    const float* W  = (i < D * D) ? W1 : W2;
    _Float16*   Wt  = (i < D * D) ? Wt1 : Wt2;
    int j = i & (D * D - 1);
    int k = j >> 7, c = j & 127;
    Wt[c * D + k] = (_Float16)W[j];
}

// ---------- per-graph start offsets (batch is sorted) ----------
__global__ void gb_kernel(const int* __restrict__ batch, int* __restrict__ gptr) {
    int g = blockIdx.x * blockDim.x + threadIdx.x;
    if (g > NG) return;
    int lo = 0, hi = NN;
    while (lo < hi) { int mid = (lo + hi) >> 1; if (batch[mid] < g) lo = mid + 1; else hi = mid; }
    gptr[g] = lo;
}

// ---------- scan pass 1 ----------
__global__ void scan1(const unsigned* __restrict__ deg, unsigned* __restrict__ chunk,
                      unsigned* __restrict__ partials) {
    __shared__ unsigned sm[256];
    int i = blockIdx.x * 256 + threadIdx.x;
    unsigned v = (i < NN) ? deg[i] : 0u;
    sm[threadIdx.x] = v;
    __syncthreads();
    for (int off = 1; off < 256; off <<= 1) {
        unsigned t = (threadIdx.x >= off) ? sm[threadIdx.x - off] : 0u;
        __syncthreads();
        sm[threadIdx.x] += t;
        __syncthreads();
    }
    if (i < NN) chunk[i] = sm[threadIdx.x];
    if (threadIdx.x == 255) partials[blockIdx.x] = sm[255];
}

// ---------- scan pass 2 ----------
__global__ void scan2(unsigned* __restrict__ partials, int nb) {
    __shared__ unsigned sm[256];
    int i = threadIdx.x;
    sm[i] = (i < nb) ? partials[i] : 0u;
    __syncthreads();
    for (int off = 1; off < 256; off <<= 1) {
        unsigned t = (i >= off) ? sm[i - off] : 0u;
        __syncthreads();
        sm[i] += t;
        __syncthreads();
    }
    if (i < nb) partials[i] = sm[i];
}

// ---------- scan pass 3 ----------
__global__ void scan3(const unsigned* __restrict__ chunk, const unsigned* __restrict__ deg,
                      const unsigned* __restrict__ pscan, int* __restrict__ ptr,
                      int* __restrict__ fill) {
    int i = blockIdx.x * 256 + threadIdx.x;
    if (i < NN) {
        unsigned off = blockIdx.x ? pscan[blockIdx.x - 1] : 0u;
        int excl = (int)(chunk[i] - deg[i] + off);
        ptr[i] = excl;
        fill[i] = excl;
    }
    if (i == 0) ptr[NN] = NT;
}

// ---------- CSR build: scatter src indices ----------
__global__ void scatter_kernel(const int* __restrict__ ei0, const int* __restrict__ ei1,
                               int* __restrict__ fill, int* __restrict__ csr_src) {
    int e = blockIdx.x * blockDim.x + threadIdx.x;
    if (e >= NT) return;
    int s, d;
    if (e < NE) { s = ei0[e]; d = ei1[e]; } else { s = d = e - NE; }
    int pos = atomicAdd(fill + d, 1);
    csr_src[pos] = s;
}

// ---------- MFMA GEMM: Hh(fp16) = X @ W, + full alpha dots ------------------
// 256 threads = 4 waves; block covers 64 rows x 128 cols; wave = 16 rows.
// v_mfma_f32_16x16x32_f16: A row=lane&15, k=8*(lane>>4)+j ; C/D col=lane&15,
// row=4*(lane>>4)+reg. B from Wt[c][k] (transposed fp16, L1/L2-resident).
template <bool FP16IN>
__global__ __launch_bounds__(256) void gemm_mfma(
    const void* __restrict__ Xv, const _Float16* __restrict__ Wt,
    const float* __restrict__ a_s, const float* __restrict__ a_d,
    __half2* __restrict__ Hh, float* __restrict__ AS, float* __restrict__ AD)
{
    __shared__ _Float16 Ht[64][132];     // padded: write ~conflict-free, read 2-way
    int t = threadIdx.x;
    int w = t >> 6, lane = t & 63;
    int rowlane = lane & 15, kg = lane >> 4;
    int rb = (int)blockIdx.x * 64;
    int r0 = rb + w * 16;
    int r  = r0 + rowlane;
    int rc = r < NN ? r : NN - 1;        // clamp; results discarded for r>=NN

    half8 afr[4];
    if constexpr (FP16IN) {
        const _Float16* xr = (const _Float16*)Xv + (size_t)rc * D + kg * 8;
        #pragma unroll
        for (int kt = 0; kt < 4; ++kt)
            afr[kt] = *reinterpret_cast<const half8*>(xr + kt * 32);
    } else {
        const float* xr = (const float*)Xv + (size_t)rc * D + kg * 8;
        #pragma unroll
        for (int kt = 0; kt < 4; ++kt) {
            float4 u = *reinterpret_cast<const float4*>(xr + kt * 32);
            float4 v = *reinterpret_cast<const float4*>(xr + kt * 32 + 4);
            half8 a;
            a[0] = (_Float16)u.x; a[1] = (_Float16)u.y;
            a[2] = (_Float16)u.z; a[3] = (_Float16)u.w;
            a[4] = (_Float16)v.x; a[5] = (_Float16)v.y;
            a[6] = (_Float16)v.z; a[7] = (_Float16)v.w;
            afr[kt] = a;
        }
    }

    f32x4 acc[8];
    #pragma unroll
    for (int i = 0; i < 8; ++i) acc[i] = (f32x4){0.f, 0.f, 0.f, 0.f};

    const _Float16* wb = Wt + (size_t)rowlane * D + kg * 8;
    #pragma unroll
    for (int ct = 0; ct < 8; ++ct) {
        const _Float16* wc = wb + (size_t)ct * 16 * D;
        #pragma unroll
        for (int kt = 0; kt < 4; ++kt) {
            half8 b = *reinterpret_cast<const half8*>(wc + kt * 32);
            acc[ct] = __builtin_amdgcn_mfma_f32_16x16x32_f16(afr[kt], b, acc[ct], 0, 0, 0);
        }
    }

    // epilogue: alpha dots (reduce over 16 col-lanes) + fp16 H via LDS
    float rs[4] = {0.f, 0.f, 0.f, 0.f}, rd[4] = {0.f, 0.f, 0.f, 0.f};
    #pragma unroll
    for (int ct = 0; ct < 8; ++ct) {
        float as_c = a_s[ct * 16 + rowlane];
        float ad_c = a_d[ct * 16 + rowlane];
        #pragma unroll
        for (int reg = 0; reg < 4; ++reg) {
            float v = acc[ct][reg];
            rs[reg] += v * as_c;
            rd[reg] += v * ad_c;
            Ht[w * 16 + kg * 4 + reg][ct * 16 + rowlane] = (_Float16)v;
        }
    }
    #pragma unroll
    for (int reg = 0; reg < 4; ++reg) {
        #pragma unroll
        for (int off = 1; off < 16; off <<= 1) {
            rs[reg] += __shfl_xor(rs[reg], off, 64);
            rd[reg] += __shfl_xor(rd[reg], off, 64);
        }
    }
    if (rowlane == 0) {
        #pragma unroll
        for (int reg = 0; reg < 4; ++reg) {
            int rr = r0 + kg * 4 + reg;
            if (rr < NN) { AS[rr] = rs[reg]; AD[rr] = rd[reg]; }
        }
    }
    __syncthreads();
    #pragma unroll
    for (int it = 0; it < 8; ++it) {
        int u = t + it * 256;            // 0..2047 dword2 units
        int row = u >> 5, cu = u & 31;
        int g = rb + row;
        if (g < NN) {
            uint2 v = *reinterpret_cast<const uint2*>(&Ht[row][cu * 4]);
            *reinterpret_cast<uint2*>(Hh + (size_t)g * 64 + cu * 2) = v;
        }
    }
}

// ---------- fused per-node GAT: two-phase, fp16 gather, fp16 out ------------
__device__ __forceinline__ float readlane_f(float v, int l) {
    return __int_as_float(__builtin_amdgcn_readlane(__float_as_int(v), l));
}

__global__ __launch_bounds__(256) void gat_node(
    const int* __restrict__ ptr, const int* __restrict__ csr_src,
    const float* __restrict__ AS, const float* __restrict__ AD,
    const __half2* __restrict__ Hh, const float* __restrict__ B,
    __half2* __restrict__ HOUT)
{
    int nid  = (int)((blockIdx.x * blockDim.x + threadIdx.x) >> 6);
    int lane = threadIdx.x & 63;
    if (nid >= NN) return;

    int beg = ptr[nid], end = ptr[nid + 1];
    int deg = end - beg;
    float ad_d = AD[nid];

    float m = -3.0e38f, den = 0.f;
    float hx = 0.f, hy = 0.f;
    const __half2* hb = Hh + lane;       // row stride = 64 half2

    for (int c0 = 0; c0 < deg; c0 += 64) {
        int cnt = deg - c0; if (cnt > 64) cnt = 64;

        // ---- phase 1: lane-parallel scores + wave softmax ----
        int   s_l = 0;
        float e_l = -3.0e38f;
        if (lane < cnt) {
            s_l = csr_src[beg + c0 + lane];
            float e = AS[s_l] + ad_d;
            e_l = e > 0.f ? e : e * NEG_SLOPE;
        }
        float cm = e_l;
        #pragma unroll
        for (int off = 32; off; off >>= 1)
            cm = fmaxf(cm, __shfl_xor(cm, off, 64));
        float mn = fmaxf(m, cm);
        float w_l = (lane < cnt) ? __expf(e_l - mn) : 0.f;
        float cs = w_l;
        #pragma unroll
        for (int off = 32; off; off >>= 1)
            cs += __shfl_xor(cs, off, 64);
        float f = __expf(m - mn);
        den = den * f + cs;
        hx *= f; hy *= f;
        m = mn;

        // ---- phase 2: broadcast-weighted fp16 gather, 8 loads in flight ----
        int j = 0;
        for (; j + 8 <= cnt; j += 8) {
            int   s0 = __builtin_amdgcn_readlane(s_l, j);
            int   s1 = __builtin_amdgcn_readlane(s_l, j + 1);
            int   s2 = __builtin_amdgcn_readlane(s_l, j + 2);
            int   s3 = __builtin_amdgcn_readlane(s_l, j + 3);
            int   s4 = __builtin_amdgcn_readlane(s_l, j + 4);
            int   s5 = __builtin_amdgcn_readlane(s_l, j + 5);
            int   s6 = __builtin_amdgcn_readlane(s_l, j + 6);
            int   s7 = __builtin_amdgcn_readlane(s_l, j + 7);
            float w0 = readlane_f(w_l, j);
            float w1 = readlane_f(w_l, j + 1);
            float w2 = readlane_f(w_l, j + 2);
            float w3 = readlane_f(w_l, j + 3);
            float w4 = readlane_f(w_l, j + 4);
            float w5 = readlane_f(w_l, j + 5);
            float w6 = readlane_f(w_l, j + 6);
            float w7 = readlane_f(w_l, j + 7);
            float2 h0 = __half22float2(hb[(size_t)s0 * 64]);
            float2 h1 = __half22float2(hb[(size_t)s1 * 64]);
            float2 h2 = __half22float2(hb[(size_t)s2 * 64]);
            float2 h3 = __half22float2(hb[(size_t)s3 * 64]);
            float2 h4 = __half22float2(hb[(size_t)s4 * 64]);
            float2 h5 = __half22float2(hb[(size_t)s5 * 64]);
            float2 h6 = __half22float2(hb[(size_t)s6 * 64]);
            float2 h7 = __half22float2(hb[(size_t)s7 * 64]);
            hx += w0 * h0.x; hy += w0 * h0.y;
            hx += w1 * h1.x; hy += w1 * h1.y;
            hx += w2 * h2.x; hy += w2 * h2.y;
            hx += w3 * h3.x; hy += w3 * h3.y;
            hx += w4 * h4.x; hy += w4 * h4.y;
            hx += w5 * h5.x; hy += w5 * h5.y;
            hx += w6 * h6.x; hy += w6 * h6.y;
            hx += w7 * h7.x; hy += w7 * h7.y;
        }
        for (; j + 4 <= cnt; j += 4) {
            int   s0 = __builtin_amdgcn_readlane(s_l, j);
            int   s1 = __builtin_amdgcn_readlane(s_l, j + 1);
            int   s2 = __builtin_amdgcn_readlane(s_l, j + 2);
            int   s3 = __builtin_amdgcn_readlane(s_l, j + 3);
            float w0 = readlane_f(w_l, j);
            float w1 = readlane_f(w_l, j + 1);
            float w2 = readlane_f(w_l, j + 2);
            float w3 = readlane_f(w_l, j + 3);
            float2 h0 = __half22float2(hb[(size_t)s0 * 64]);
            float2 h1 = __half22float2(hb[(size_t)s1 * 64]);
            float2 h2 = __half22float2(hb[(size_t)s2 * 64]);
            float2 h3 = __half22float2(hb[(size_t)s3 * 64]);
            hx += w0 * h0.x; hy += w0 * h0.y;
            hx += w1 * h1.x; hy += w1 * h1.y;
            hx += w2 * h2.x; hy += w2 * h2.y;
            hx += w3 * h3.x; hy += w3 * h3.y;
        }
        for (; j < cnt; ++j) {
            int   s0 = __builtin_amdgcn_readlane(s_l, j);
            float w0 = readlane_f(w_l, j);
            float2 h0 = __half22float2(hb[(size_t)s0 * 64]);
            hx += w0 * h0.x; hy += w0 * h0.y;
        }
    }

    float inv = 1.0f / den;
    float2 bv = *reinterpret_cast<const float2*>(B + lane * 2);
    float ox = fmaxf(hx * inv + bv.x, 0.f);
    float oy = fmaxf(hy * inv + bv.y, 0.f);
    HOUT[(size_t)nid * 64 + lane] = __floats2half2_rn(ox, oy);
}

// ---------- mean pool: one block per graph, zero atomics ----------
__global__ __launch_bounds__(128) void pool_kernel(
    const __half* __restrict__ houth, const int* __restrict__ gptr,
    float* __restrict__ OUT)
{
    int g = blockIdx.x, c = threadIdx.x;
    int lo = gptr[g], hi = gptr[g + 1];
    float s0 = 0.f, s1 = 0.f, s2 = 0.f, s3 = 0.f;
    int r = lo;
    for (; r + 4 <= hi; r += 4) {
        s0 += __half2float(houth[(size_t)(r + 0) * D + c]);
        s1 += __half2float(houth[(size_t)(r + 1) * D + c]);
        s2 += __half2float(houth[(size_t)(r + 2) * D + c]);
        s3 += __half2float(houth[(size_t)(r + 3) * D + c]);
    }
    for (; r < hi; ++r) s0 += __half2float(houth[(size_t)r * D + c]);
    float s = (s0 + s1) + (s2 + s3);
    float n = (float)(hi - lo);
    OUT[(size_t)g * D + c] = s / fmaxf(n, 1.f);
}

extern "C" void kernel_launch(void* const* d_in, const int* in_sizes, int n_in,
                              void* d_out, int out_size, void* d_ws, size_t ws_size,
                              hipStream_t stream)
{
    const float* x     = (const float*)d_in[0];
    const int*   ei    = (const int*)d_in[1];
    const int*   batch = (const int*)d_in[2];
    const float* W[2]    = { (const float*)d_in[3], (const float*)d_in[7] };
    const float* ASV[2]  = { (const float*)d_in[4], (const float*)d_in[8] };
    const float* ADV[2]  = { (const float*)d_in[5], (const float*)d_in[9] };
    const float* BV[2]   = { (const float*)d_in[6], (const float*)d_in[10] };
    float* out = (float*)d_out;
    float* ws  = (float*)d_ws;

    const int* ei0 = ei;
    const int* ei1 = ei + NE;

    const int NB = (NN + 255) / 256;

    // ---- workspace layout (32-bit words) ----
    size_t o = 0;
    unsigned* deg   = (unsigned*)(ws + o); o += NN;               // zeroed
    __half2*  Hh    = (__half2*)(ws + o);  o += (size_t)NN * 64;  // fp16 H (gemm out)
    __half2*  houth = (__half2*)(ws + o);  o += (size_t)NN * 64;  // fp16 gat out
    float*    asb   = ws + o;              o += NN;
    float*    adb   = ws + o;              o += NN;
    unsigned* chunk = (unsigned*)(ws + o); o += NN;
    int*      ptr   = (int*)(ws + o);      o += NN + 1;
    int*      fill  = (int*)(ws + o);      o += NN;
    int*      csr   = (int*)(ws + o);      o += NT;
    unsigned* parts = (unsigned*)(ws + o); o += 256;
    int*      gptr  = (int*)(ws + o);      o += NG + 1;
    _Float16* Wt1   = (_Float16*)(ws + o); o += (D * D) / 2;
    _Float16* Wt2   = (_Float16*)(ws + o); o += (D * D) / 2;

    const int edge_blocks = (NT + 255) / 256;
    const int gemm_blocks = (NN + 63) / 64;
    const int gat_blocks  = (NN + 3) / 4;

    // ---- one-time graph prep ----
    zero_kernel<<<49, 256, 0, stream>>>((float4*)deg, NN / 4);
    hist_kernel<<<edge_blocks, 256, 0, stream>>>(ei1, deg);
    wt_kernel<<<(2 * D * D + 255) / 256, 256, 0, stream>>>(W[0], W[1], Wt1, Wt2);
    gb_kernel<<<(NG + 256) / 256, 256, 0, stream>>>(batch, gptr);
    scan1<<<NB, 256, 0, stream>>>(deg, chunk, parts);
    scan2<<<1, 256, 0, stream>>>(parts, NB);
    scan3<<<NB, 256, 0, stream>>>(chunk, deg, parts, ptr, fill);
    scatter_kernel<<<edge_blocks, 256, 0, stream>>>(ei0, ei1, fill, csr);

    // ---- layer 1 ----
    gemm_mfma<false><<<gemm_blocks, 256, 0, stream>>>(x, Wt1, ASV[0], ADV[0],
                                                      Hh, asb, adb);
    gat_node<<<gat_blocks, 256, 0, stream>>>(ptr, csr, asb, adb, Hh, BV[0], houth);
    pool_kernel<<<NG, 128, 0, stream>>>((const __half*)houth, gptr, out);

    // ---- layer 2 (input = fp16 houth) ----
    gemm_mfma<true><<<gemm_blocks, 256, 0, stream>>>(houth, Wt2, ASV[1], ADV[1],
                                                     Hh, asb, adb);
    gat_node<<<gat_blocks, 256, 0, stream>>>(ptr, csr, asb, adb, Hh, BV[1], houth);
    pool_kernel<<<NG, 128, 0, stream>>>((const __half*)houth, gptr, out + (size_t)NG * D);
}

// Round 7
// 204.322 us; speedup vs baseline: 5.6004x; 1.0536x over previous
//
#include <hip/hip_runtime.h>
#include <hip/hip_fp16.h>
#include <cstdint>
#include <cstddef>

#define NN 50000
#define NE 600000
#define NT (NE + NN)          // 650000 edges incl. self loops
#define NG 1024
#define D 128
#define NEG_SLOPE 0.2f

typedef _Float16 half8 __attribute__((ext_vector_type(8)));
typedef float f32x4 __attribute__((ext_vector_type(4)));

// ---------- fused misc prep: zero deg + fp16-transpose W + graph offsets ----
__global__ void prep_misc(const float* __restrict__ W1, const float* __restrict__ W2,
                          _Float16* __restrict__ Wt1, _Float16* __restrict__ Wt2,
                          const int* __restrict__ batch, int* __restrict__ gptr,
                          unsigned* __restrict__ deg) {
    int i = blockIdx.x * 256 + threadIdx.x;
    if (i < NN) deg[i] = 0u;
    if (i < 2 * D * D) {
        const float* W  = (i < D * D) ? W1 : W2;
        _Float16*   Wt  = (i < D * D) ? Wt1 : Wt2;
        int j = i & (D * D - 1);
        int k = j >> 7, c = j & 127;
        Wt[c * D + k] = (_Float16)W[j];
    }
    if (i <= NG) {
        int lo = 0, hi = NN;
        while (lo < hi) { int mid = (lo + hi) >> 1; if (batch[mid] < i) lo = mid + 1; else hi = mid; }
        gptr[i] = lo;
    }
}

// ---------- dst histogram ----------
__global__ void hist_kernel(const int* __restrict__ ei1, unsigned* __restrict__ deg) {
    int e = blockIdx.x * blockDim.x + threadIdx.x;
    if (e >= NT) return;
    int d = (e < NE) ? ei1[e] : (e - NE);
    atomicAdd(deg + d, 1u);
}

// ---------- scan pass 1 ----------
__global__ void scan1(const unsigned* __restrict__ deg, unsigned* __restrict__ chunk,
                      unsigned* __restrict__ partials) {
    __shared__ unsigned sm[256];
    int i = blockIdx.x * 256 + threadIdx.x;
    unsigned v = (i < NN) ? deg[i] : 0u;
    sm[threadIdx.x] = v;
    __syncthreads();
    for (int off = 1; off < 256; off <<= 1) {
        unsigned t = (threadIdx.x >= off) ? sm[threadIdx.x - off] : 0u;
        __syncthreads();
        sm[threadIdx.x] += t;
        __syncthreads();
    }
    if (i < NN) chunk[i] = sm[threadIdx.x];
    if (threadIdx.x == 255) partials[blockIdx.x] = sm[255];
}

// ---------- scan pass 2 ----------
__global__ void scan2(unsigned* __restrict__ partials, int nb) {
    __shared__ unsigned sm[256];
    int i = threadIdx.x;
    sm[i] = (i < nb) ? partials[i] : 0u;
    __syncthreads();
    for (int off = 1; off < 256; off <<= 1) {
        unsigned t = (i >= off) ? sm[i - off] : 0u;
        __syncthreads();
        sm[i] += t;
        __syncthreads();
    }
    if (i < nb) partials[i] = sm[i];
}

// ---------- scan pass 3 ----------
__global__ void scan3(const unsigned* __restrict__ chunk, const unsigned* __restrict__ deg,
                      const unsigned* __restrict__ pscan, int* __restrict__ ptr,
                      int* __restrict__ fill) {
    int i = blockIdx.x * 256 + threadIdx.x;
    if (i < NN) {
        unsigned off = blockIdx.x ? pscan[blockIdx.x - 1] : 0u;
        int excl = (int)(chunk[i] - deg[i] + off);
        ptr[i] = excl;
        fill[i] = excl;
    }
    if (i == 0) ptr[NN] = NT;
}

// ---------- CSR build: scatter src indices ----------
__global__ void scatter_kernel(const int* __restrict__ ei0, const int* __restrict__ ei1,
                               int* __restrict__ fill, int* __restrict__ csr_src) {
    int e = blockIdx.x * blockDim.x + threadIdx.x;
    if (e >= NT) return;
    int s, d;
    if (e < NE) { s = ei0[e]; d = ei1[e]; } else { s = d = e - NE; }
    int pos = atomicAdd(fill + d, 1);
    csr_src[pos] = s;
}

// ---------- MFMA GEMM: Hh(fp16) = X @ W, + full alpha dots ------------------
template <bool FP16IN>
__global__ __launch_bounds__(256) void gemm_mfma(
    const void* __restrict__ Xv, const _Float16* __restrict__ Wt,
    const float* __restrict__ a_s, const float* __restrict__ a_d,
    __half2* __restrict__ Hh, float* __restrict__ AS, float* __restrict__ AD)
{
    __shared__ _Float16 Ht[64][132];
    int t = threadIdx.x;
    int w = t >> 6, lane = t & 63;
    int rowlane = lane & 15, kg = lane >> 4;
    int rb = (int)blockIdx.x * 64;
    int r0 = rb + w * 16;
    int r  = r0 + rowlane;
    int rc = r < NN ? r : NN - 1;

    half8 afr[4];
    if constexpr (FP16IN) {
        const _Float16* xr = (const _Float16*)Xv + (size_t)rc * D + kg * 8;
        #pragma unroll
        for (int kt = 0; kt < 4; ++kt)
            afr[kt] = *reinterpret_cast<const half8*>(xr + kt * 32);
    } else {
        const float* xr = (const float*)Xv + (size_t)rc * D + kg * 8;
        #pragma unroll
        for (int kt = 0; kt < 4; ++kt) {
            float4 u = *reinterpret_cast<const float4*>(xr + kt * 32);
            float4 v = *reinterpret_cast<const float4*>(xr + kt * 32 + 4);
            half8 a;
            a[0] = (_Float16)u.x; a[1] = (_Float16)u.y;
            a[2] = (_Float16)u.z; a[3] = (_Float16)u.w;
            a[4] = (_Float16)v.x; a[5] = (_Float16)v.y;
            a[6] = (_Float16)v.z; a[7] = (_Float16)v.w;
            afr[kt] = a;
        }
    }

    f32x4 acc[8];
    #pragma unroll
    for (int i = 0; i < 8; ++i) acc[i] = (f32x4){0.f, 0.f, 0.f, 0.f};

    const _Float16* wb = Wt + (size_t)rowlane * D + kg * 8;
    #pragma unroll
    for (int ct = 0; ct < 8; ++ct) {
        const _Float16* wc = wb + (size_t)ct * 16 * D;
        #pragma unroll
        for (int kt = 0; kt < 4; ++kt) {
            half8 b = *reinterpret_cast<const half8*>(wc + kt * 32);
            acc[ct] = __builtin_amdgcn_mfma_f32_16x16x32_f16(afr[kt], b, acc[ct], 0, 0, 0);
        }
    }

    float rs[4] = {0.f, 0.f, 0.f, 0.f}, rd[4] = {0.f, 0.f, 0.f, 0.f};
    #pragma unroll
    for (int ct = 0; ct < 8; ++ct) {
        float as_c = a_s[ct * 16 + rowlane];
        float ad_c = a_d[ct * 16 + rowlane];
        #pragma unroll
        for (int reg = 0; reg < 4; ++reg) {
            float v = acc[ct][reg];
            rs[reg] += v * as_c;
            rd[reg] += v * ad_c;
            Ht[w * 16 + kg * 4 + reg][ct * 16 + rowlane] = (_Float16)v;
        }
    }
    #pragma unroll
    for (int reg = 0; reg < 4; ++reg) {
        #pragma unroll
        for (int off = 1; off < 16; off <<= 1) {
            rs[reg] += __shfl_xor(rs[reg], off, 64);
            rd[reg] += __shfl_xor(rd[reg], off, 64);
        }
    }
    if (rowlane == 0) {
        #pragma unroll
        for (int reg = 0; reg < 4; ++reg) {
            int rr = r0 + kg * 4 + reg;
            if (rr < NN) { AS[rr] = rs[reg]; AD[rr] = rd[reg]; }
        }
    }
    __syncthreads();
    #pragma unroll
    for (int it = 0; it < 8; ++it) {
        int u = t + it * 256;
        int row = u >> 5, cu = u & 31;
        int g = rb + row;
        if (g < NN) {
            uint2 v = *reinterpret_cast<const uint2*>(&Ht[row][cu * 4]);
            *reinterpret_cast<uint2*>(Hh + (size_t)g * 64 + cu * 2) = v;
        }
    }
}

// ---------- fused per-node GAT: 32-lane groups, 2 nodes/wave ----------------
__device__ __forceinline__ void acc4(float w, uint2 v,
                                     float& a0, float& a1, float& a2, float& a3) {
    float2 lo = __half22float2(*reinterpret_cast<const __half2*>(&v.x));
    float2 hi = __half22float2(*reinterpret_cast<const __half2*>(&v.y));
    a0 += w * lo.x; a1 += w * lo.y; a2 += w * hi.x; a3 += w * hi.y;
}
__device__ __forceinline__ float shfl_f32(float v, int l) {
    return __shfl(v, l, 32);
}

__global__ __launch_bounds__(256) void gat_node(
    const int* __restrict__ ptr, const int* __restrict__ csr_src,
    const float* __restrict__ AS, const float* __restrict__ AD,
    const uint2* __restrict__ Hh, const float* __restrict__ B,
    uint2* __restrict__ HOUT)
{
    int wid  = (int)((blockIdx.x * blockDim.x + threadIdx.x) >> 6);
    int lane = threadIdx.x & 63;
    int l32  = lane & 31;
    int nid  = wid * 2 + (lane >> 5);
    if (nid >= NN) return;

    int beg = ptr[nid], end = ptr[nid + 1];
    int deg = end - beg;
    float ad_d = AD[nid];

    float m = -3.0e38f, den = 0.f;
    float a0 = 0.f, a1 = 0.f, a2 = 0.f, a3 = 0.f;
    const uint2* hb = Hh + l32;          // row stride = 32 uint2 (256 B)

    for (int c0 = 0; c0 < deg; c0 += 32) {
        int cnt = deg - c0; if (cnt > 32) cnt = 32;

        // ---- phase 1: lane-parallel scores + 32-lane softmax ----
        int   s_l = 0;
        float e_l = -3.0e38f;
        if (l32 < cnt) {
            s_l = csr_src[beg + c0 + l32];
            float e = AS[s_l] + ad_d;
            e_l = e > 0.f ? e : e * NEG_SLOPE;
        }
        float cm = e_l;
        #pragma unroll
        for (int off = 16; off; off >>= 1)
            cm = fmaxf(cm, __shfl_xor(cm, off, 32));
        float mn = fmaxf(m, cm);
        float w_l = (l32 < cnt) ? __expf(e_l - mn) : 0.f;
        float cs = w_l;
        #pragma unroll
        for (int off = 16; off; off >>= 1)
            cs += __shfl_xor(cs, off, 32);
        float f = __expf(m - mn);
        den = den * f + cs;
        a0 *= f; a1 *= f; a2 *= f; a3 *= f;
        m = mn;

        // ---- phase 2: group-broadcast weighted gather, 8 loads in flight ----
        int j = 0;
        for (; j + 8 <= cnt; j += 8) {
            int   s0 = __shfl(s_l, j,     32);
            int   s1 = __shfl(s_l, j + 1, 32);
            int   s2 = __shfl(s_l, j + 2, 32);
            int   s3 = __shfl(s_l, j + 3, 32);
            int   s4 = __shfl(s_l, j + 4, 32);
            int   s5 = __shfl(s_l, j + 5, 32);
            int   s6 = __shfl(s_l, j + 6, 32);
            int   s7 = __shfl(s_l, j + 7, 32);
            float w0 = shfl_f32(w_l, j);
            float w1 = shfl_f32(w_l, j + 1);
            float w2 = shfl_f32(w_l, j + 2);
            float w3 = shfl_f32(w_l, j + 3);
            float w4 = shfl_f32(w_l, j + 4);
            float w5 = shfl_f32(w_l, j + 5);
            float w6 = shfl_f32(w_l, j + 6);
            float w7 = shfl_f32(w_l, j + 7);
            uint2 h0 = hb[(size_t)s0 * 32];
            uint2 h1 = hb[(size_t)s1 * 32];
            uint2 h2 = hb[(size_t)s2 * 32];
            uint2 h3 = hb[(size_t)s3 * 32];
            uint2 h4 = hb[(size_t)s4 * 32];
            uint2 h5 = hb[(size_t)s5 * 32];
            uint2 h6 = hb[(size_t)s6 * 32];
            uint2 h7 = hb[(size_t)s7 * 32];
            acc4(w0, h0, a0, a1, a2, a3);
            acc4(w1, h1, a0, a1, a2, a3);
            acc4(w2, h2, a0, a1, a2, a3);
            acc4(w3, h3, a0, a1, a2, a3);
            acc4(w4, h4, a0, a1, a2, a3);
            acc4(w5, h5, a0, a1, a2, a3);
            acc4(w6, h6, a0, a1, a2, a3);
            acc4(w7, h7, a0, a1, a2, a3);
        }
        for (; j + 4 <= cnt; j += 4) {
            int   s0 = __shfl(s_l, j,     32);
            int   s1 = __shfl(s_l, j + 1, 32);
            int   s2 = __shfl(s_l, j + 2, 32);
            int   s3 = __shfl(s_l, j + 3, 32);
            float w0 = shfl_f32(w_l, j);
            float w1 = shfl_f32(w_l, j + 1);
            float w2 = shfl_f32(w_l, j + 2);
            float w3 = shfl_f32(w_l, j + 3);
            uint2 h0 = hb[(size_t)s0 * 32];
            uint2 h1 = hb[(size_t)s1 * 32];
            uint2 h2 = hb[(size_t)s2 * 32];
            uint2 h3 = hb[(size_t)s3 * 32];
            acc4(w0, h0, a0, a1, a2, a3);
            acc4(w1, h1, a0, a1, a2, a3);
            acc4(w2, h2, a0, a1, a2, a3);
            acc4(w3, h3, a0, a1, a2, a3);
        }
        for (; j < cnt; ++j) {
            int   s0 = __shfl(s_l, j, 32);
            float w0 = shfl_f32(w_l, j);
            uint2 h0 = hb[(size_t)s0 * 32];
            acc4(w0, h0, a0, a1, a2, a3);
        }
    }

    float inv = 1.0f / den;
    float4 bv = *reinterpret_cast<const float4*>(B + l32 * 4);
    float o0 = fmaxf(a0 * inv + bv.x, 0.f);
    float o1 = fmaxf(a1 * inv + bv.y, 0.f);
    float o2 = fmaxf(a2 * inv + bv.z, 0.f);
    float o3 = fmaxf(a3 * inv + bv.w, 0.f);
    __half2 p0 = __floats2half2_rn(o0, o1);
    __half2 p1 = __floats2half2_rn(o2, o3);
    uint2 pv;
    pv.x = *reinterpret_cast<unsigned*>(&p0);
    pv.y = *reinterpret_cast<unsigned*>(&p1);
    HOUT[(size_t)nid * 32 + l32] = pv;
}

// ---------- mean pool: one block per graph, zero atomics ----------
__global__ __launch_bounds__(128) void pool_kernel(
    const __half* __restrict__ houth, const int* __restrict__ gptr,
    float* __restrict__ OUT)
{
    int g = blockIdx.x, c = threadIdx.x;
    int lo = gptr[g], hi = gptr[g + 1];
    float s0 = 0.f, s1 = 0.f, s2 = 0.f, s3 = 0.f;
    int r = lo;
    for (; r + 4 <= hi; r += 4) {
        s0 += __half2float(houth[(size_t)(r + 0) * D + c]);
        s1 += __half2float(houth[(size_t)(r + 1) * D + c]);
        s2 += __half2float(houth[(size_t)(r + 2) * D + c]);
        s3 += __half2float(houth[(size_t)(r + 3) * D + c]);
    }
    for (; r < hi; ++r) s0 += __half2float(houth[(size_t)r * D + c]);
    float s = (s0 + s1) + (s2 + s3);
    float n = (float)(hi - lo);
    OUT[(size_t)g * D + c] = s / fmaxf(n, 1.f);
}

extern "C" void kernel_launch(void* const* d_in, const int* in_sizes, int n_in,
                              void* d_out, int out_size, void* d_ws, size_t ws_size,
                              hipStream_t stream)
{
    const float* x     = (const float*)d_in[0];
    const int*   ei    = (const int*)d_in[1];
    const int*   batch = (const int*)d_in[2];
    const float* W[2]    = { (const float*)d_in[3], (const float*)d_in[7] };
    const float* ASV[2]  = { (const float*)d_in[4], (const float*)d_in[8] };
    const float* ADV[2]  = { (const float*)d_in[5], (const float*)d_in[9] };
    const float* BV[2]   = { (const float*)d_in[6], (const float*)d_in[10] };
    float* out = (float*)d_out;
    float* ws  = (float*)d_ws;

    const int* ei0 = ei;
    const int* ei1 = ei + NE;

    const int NB = (NN + 255) / 256;

    // ---- workspace layout (32-bit words) ----
    size_t o = 0;
    unsigned* deg   = (unsigned*)(ws + o); o += NN;
    __half2*  Hh    = (__half2*)(ws + o);  o += (size_t)NN * 64;  // fp16 H (gemm out)
    __half2*  houth = (__half2*)(ws + o);  o += (size_t)NN * 64;  // fp16 gat out
    float*    asb   = ws + o;              o += NN;
    float*    adb   = ws + o;              o += NN;
    unsigned* chunk = (unsigned*)(ws + o); o += NN;
    int*      ptr   = (int*)(ws + o);      o += NN + 1;
    int*      fill  = (int*)(ws + o);      o += NN;
    int*      csr   = (int*)(ws + o);      o += NT;
    unsigned* parts = (unsigned*)(ws + o); o += 256;
    int*      gptr  = (int*)(ws + o);      o += NG + 1;
    _Float16* Wt1   = (_Float16*)(ws + o); o += (D * D) / 2;
    _Float16* Wt2   = (_Float16*)(ws + o); o += (D * D) / 2;

    const int edge_blocks = (NT + 255) / 256;
    const int gemm_blocks = (NN + 63) / 64;
    const int gat_blocks  = (NN / 2 + 3) / 4;      // 2 nodes/wave, 4 waves/block

    // ---- one-time graph prep ----
    prep_misc<<<NB, 256, 0, stream>>>(W[0], W[1], Wt1, Wt2, batch, gptr, deg);
    hist_kernel<<<edge_blocks, 256, 0, stream>>>(ei1, deg);
    scan1<<<NB, 256, 0, stream>>>(deg, chunk, parts);
    scan2<<<1, 256, 0, stream>>>(parts, NB);
    scan3<<<NB, 256, 0, stream>>>(chunk, deg, parts, ptr, fill);
    scatter_kernel<<<edge_blocks, 256, 0, stream>>>(ei0, ei1, fill, csr);

    // ---- layer 1 ----
    gemm_mfma<false><<<gemm_blocks, 256, 0, stream>>>(x, Wt1, ASV[0], ADV[0],
                                                      Hh, asb, adb);
    gat_node<<<gat_blocks, 256, 0, stream>>>(ptr, csr, asb, adb, (const uint2*)Hh,
                                             BV[0], (uint2*)houth);
    pool_kernel<<<NG, 128, 0, stream>>>((const __half*)houth, gptr, out);

    // ---- layer 2 (input = fp16 houth) ----
    gemm_mfma<true><<<gemm_blocks, 256, 0, stream>>>(houth, Wt2, ASV[1], ADV[1],
                                                     Hh, asb, adb);
    gat_node<<<gat_blocks, 256, 0, stream>>>(ptr, csr, asb, adb, (const uint2*)Hh,
                                             BV[1], (uint2*)houth);
    pool_kernel<<<NG, 128, 0, stream>>>((const __half*)houth, gptr, out + (size_t)NG * D);
}